// Round 11
// baseline (156.403 us; speedup 1.0000x reference)
//
#include <hip/hip_runtime.h>
#include <hip/hip_bf16.h>

typedef __bf16 bf16x8 __attribute__((ext_vector_type(8)));
typedef __bf16 bf16x4 __attribute__((ext_vector_type(4)));
typedef float f32x4 __attribute__((ext_vector_type(4)));

#define SEQ   2048
#define NB    2
#define NTOK  4096
#define HIDD  512
#define NHEAD 16
#define DHEAD 64
#define QKVN  3072
#define GUN   2048

// workspace layout (bytes)
#define OFF_WQKVT  0u
#define OFF_WOT    3145728u
#define OFF_WGUT   4194304u
#define OFF_WDT    6291456u
#define OFF_HB     7340032u
#define OFF_QKV    11534336u
#define OFF_ATTN   36700160u
#define OFF_H2     45088768u
#define OFF_G      53477376u
#define OFF_M      (OFF_QKV + 16777216u)

#define QSCALE 0.1803368801111731f           // 0.125 * log2(e): exp2-domain scores

#if __has_builtin(__builtin_amdgcn_exp2f)
#define EXP2(x) __builtin_amdgcn_exp2f(x)
#else
#define EXP2(x) exp2f(x)
#endif

typedef unsigned int __attribute__((address_space(1))) as1_uint;
typedef unsigned int __attribute__((address_space(3))) as3_uint;
__device__ __forceinline__ void gload16(const void* g, void* l) {
    __builtin_amdgcn_global_load_lds((const as1_uint*)g, (as3_uint*)l, 16, 0, 0);
}

// ---------------- fused prep: 7 weight transposes + rmsnorm1, one launch ----
__global__ __launch_bounds__(256) void prep_k(
    const float* __restrict__ wq, const float* __restrict__ wk,
    const float* __restrict__ wv, const float* __restrict__ wo,
    const float* __restrict__ wg, const float* __restrict__ wu,
    const float* __restrict__ wd,
    __bf16* __restrict__ qkvT, __bf16* __restrict__ woT,
    __bf16* __restrict__ wguT, __bf16* __restrict__ wdT,
    const float* __restrict__ x, const float* __restrict__ norm1,
    __bf16* __restrict__ hb) {
    __shared__ float t[32][33];
    int bid = blockIdx.x;
    if (bid < 3584) {
        int which = bid >> 9, bx = bid & 511;
        const float* in; __bf16* out; int K, N, mode = 0, phase = 0;
        switch (which) {
            case 0: in = wq; out = qkvT;              K = 512;  N = 1024; break;
            case 1: in = wk; out = qkvT + 1024 * 512; K = 512;  N = 1024; break;
            case 2: in = wv; out = qkvT + 2048 * 512; K = 512;  N = 1024; break;
            case 3: in = wo; out = woT;               K = 1024; N = 512;  break;
            case 4: in = wg; out = wguT;              K = 512;  N = 1024; mode = 1; phase = 0; break;
            case 5: in = wu; out = wguT;              K = 512;  N = 1024; mode = 1; phase = 1; break;
            default: in = wd; out = wdT;              K = 1024; N = 512;  break;
        }
        int ntn = N >> 5;
        int n0 = (bx & (ntn - 1)) * 32;
        int k0 = (bx / ntn) * 32;
        int tx = threadIdx.x & 31, ty = threadIdx.x >> 5;
#pragma unroll
        for (int j = 0; j < 4; ++j)
            t[ty * 4 + j][tx] = in[(size_t)(k0 + ty * 4 + j) * N + n0 + tx];
        __syncthreads();
#pragma unroll
        for (int j = 0; j < 4; ++j) {
            int n = n0 + ty * 4 + j;
            int row = mode ? (((n >> 4) << 5) + phase * 16 + (n & 15)) : n;
            out[(size_t)row * K + k0 + tx] = (__bf16)t[tx][ty * 4 + j];
        }
    } else {
        int row = bid - 3584;
        int tt = threadIdx.x;
        const float* xr = x + (size_t)row * HIDD;
        float2 v = *(const float2*)&xr[tt * 2];
        float ss = v.x * v.x + v.y * v.y;
#pragma unroll
        for (int off = 32; off >= 1; off >>= 1) ss += __shfl_xor(ss, off);
        if ((tt & 63) == 0) t[0][tt >> 6] = ss;
        __syncthreads();
        float tot = t[0][0] + t[0][1] + t[0][2] + t[0][3];
        float r = rsqrtf(tot * (1.0f / HIDD) + 1e-8f);
        hb[(size_t)row * HIDD + tt * 2]     = (__bf16)(v.x * r * norm1[tt * 2]);
        hb[(size_t)row * HIDD + tt * 2 + 1] = (__bf16)(v.y * r * norm1[tt * 2 + 1]);
    }
}

// ---------------- RMSNorm (standalone, for norm2) ----------------
__global__ __launch_bounds__(256) void rmsnorm_k(const float* __restrict__ x,
                                                 const float* __restrict__ w,
                                                 __bf16* __restrict__ out) {
    int row = blockIdx.x;
    int t = threadIdx.x;
    const float* xr = x + (size_t)row * HIDD;
    float2 v = *(const float2*)&xr[t * 2];
    float ss = v.x * v.x + v.y * v.y;
#pragma unroll
    for (int off = 32; off >= 1; off >>= 1) ss += __shfl_xor(ss, off);
    __shared__ float red[4];
    if ((t & 63) == 0) red[t >> 6] = ss;
    __syncthreads();
    float tot = red[0] + red[1] + red[2] + red[3];
    float r = rsqrtf(tot * (1.0f / HIDD) + 1e-8f);
    out[(size_t)row * HIDD + t * 2]     = (__bf16)(v.x * r * w[t * 2]);
    out[(size_t)row * HIDD + t * 2 + 1] = (__bf16)(v.y * r * w[t * 2 + 1]);
}

// ---------------- GEMM: C[M][N] = A[M][K] * Bt[N][K]^T ----------------
// BK template param; XOR source-swizzled LDS (conflict-free ds_read_b128).
template <int EPI, int TM, int TN, int BK>
__global__ __launch_bounds__(256) void gemm_bt(const __bf16* __restrict__ A,
                                               const __bf16* __restrict__ Bt,
                                               int M, int N, int K,
                                               __bf16* __restrict__ Cb,
                                               float* __restrict__ Cf,
                                               const float* __restrict__ resid,
                                               const float* __restrict__ scale,
                                               const float* __restrict__ cosv,
                                               const float* __restrict__ sinv) {
    __shared__ alignas(16) __bf16 As[TM][BK];
    __shared__ alignas(16) __bf16 Bs[TN][BK];
    constexpr int MI = TM / 32, NI = TN / 32;
    constexpr int CPB = BK / 8;          // 16B chunks per row
    int m0 = blockIdx.y * TM, n0 = blockIdx.x * TN;
    int tid = threadIdx.x;
    int lane = tid & 63, w = tid >> 6;
    int wm = (w >> 1) * (TM / 2), wn = (w & 1) * (TN / 2);
    int lr = lane & 15, lkg = lane >> 4;
    f32x4 acc[MI][NI] = {};
    int nkt = K / BK;
    for (int kt = 0; kt < nkt; ++kt) {
        __syncthreads();
#pragma unroll
        for (int i = 0; i < (TM * BK) / 2048; ++i) {
            int c = i * 256 + tid;
            int row = c / CPB, ch = c % CPB;
            gload16(&A[(size_t)(m0 + row) * K + kt * BK + ((ch ^ (row & 7)) << 3)],
                    (__bf16*)As + c * 8);
        }
#pragma unroll
        for (int i = 0; i < (TN * BK) / 2048; ++i) {
            int c = i * 256 + tid;
            int row = c / CPB, ch = c % CPB;
            gload16(&Bt[(size_t)(n0 + row) * K + kt * BK + ((ch ^ (row & 7)) << 3)],
                    (__bf16*)Bs + c * 8);
        }
        __syncthreads();
#pragma unroll
        for (int kk = 0; kk < BK / 32; ++kk) {
            bf16x8 af[MI], bfv[NI];
#pragma unroll
            for (int mi = 0; mi < MI; ++mi) {
                int row = wm + mi * 16 + lr;
                af[mi] = *(const bf16x8*)&As[row][(((kk * 4 + lkg) ^ (row & 7)) << 3)];
            }
#pragma unroll
            for (int ni = 0; ni < NI; ++ni) {
                int row = wn + ni * 16 + lr;
                bfv[ni] = *(const bf16x8*)&Bs[row][(((kk * 4 + lkg) ^ (row & 7)) << 3)];
            }
#pragma unroll
            for (int mi = 0; mi < MI; ++mi)
#pragma unroll
                for (int ni = 0; ni < NI; ++ni)
                    acc[mi][ni] = __builtin_amdgcn_mfma_f32_16x16x32_bf16(
                        af[mi], bfv[ni], acc[mi][ni], 0, 0, 0);
        }
    }
    if (EPI == 1) {
        bool do_rope = (n0 + wn) < 2048;
        float qf = (n0 + wn) < 1024 ? QSCALE : 1.0f;
#pragma unroll
        for (int mi = 0; mi < MI; ++mi)
#pragma unroll
            for (int r = 0; r < 4; ++r) {
                int row = m0 + wm + mi * 16 + (lane >> 4) * 4 + r;
                int s = row & (SEQ - 1);
#pragma unroll
                for (int ni = 0; ni < 2; ++ni) {
                    float v1 = acc[mi][ni][r], v2 = acc[mi][ni + 2][r];
                    size_t i1 = (size_t)row * N + n0 + wn + ni * 16 + lr;
                    size_t i2 = i1 + 32;
                    if (do_rope) {
                        int d = ni * 16 + lr;
                        float c = cosv[s * 32 + d], sn = sinv[s * 32 + d];
                        Cb[i1] = (__bf16)((v1 * c - v2 * sn) * qf);
                        Cb[i2] = (__bf16)((v2 * c + v1 * sn) * qf);
                    } else {
                        Cb[i1] = (__bf16)v1;
                        Cb[i2] = (__bf16)v2;
                    }
                }
            }
    } else if (EPI == 3) {
#pragma unroll
        for (int mi = 0; mi < MI; ++mi)
#pragma unroll
            for (int r = 0; r < 4; ++r) {
                int row = m0 + wm + mi * 16 + (lane >> 4) * 4 + r;
#pragma unroll
                for (int ni = 0; ni < 4; ni += 2) {
                    float g = acc[mi][ni][r], u = acc[mi][ni + 1][r];
                    float mv = (g / (1.0f + __expf(-g))) * u;
                    int j = (((n0 + wn + ni * 16) >> 5) << 4) + lr;
                    Cb[(size_t)row * 1024 + j] = (__bf16)mv;
                }
            }
    } else {
#pragma unroll
        for (int mi = 0; mi < MI; ++mi)
#pragma unroll
            for (int ni = 0; ni < NI; ++ni)
#pragma unroll
                for (int r = 0; r < 4; ++r) {
                    int row = m0 + wm + mi * 16 + (lane >> 4) * 4 + r;
                    int col = n0 + wn + ni * 16 + lr;
                    size_t idx = (size_t)row * N + col;
                    float vv = acc[mi][ni][r];
                    if (EPI == 0) Cb[idx] = (__bf16)vv;
                    else          Cf[idx] = resid[idx] + vv * scale[col];
                }
    }
}

// ---------------- causal flash attention: K in REGISTERS, V-only LDS ----------------
// r10 diagnosis: CU LDS pipe ~80-90% occupied (8 waves x ~800 LDS-cyc/iter).
// All 4 waves use IDENTICAL K fragments (swapped-operand layout), and each
// fragment is a contiguous 16B row-slice -> load K straight from global into
// 64 VGPRs (L2-hit), deleting 16 ds_read_b128 + 4 global_load_lds per
// wave/iter (~45% of LDS traffic) and decoupling QK from LDS latency.
// V stays reg-staged -> swizzled LDS (transpose needed), dbuf 32KB.
// Phase-1 serializes tile B then tile A reusing sc[] (VGPR budget; K-sharing
// via regs preserved). Raw lgkmcnt(0)+s_barrier (no vmcnt drain: only VtF
// needs cross-wave visibility; K/V reg-loads legitimately span the barrier).
__global__ __launch_bounds__(256, 2) void attn_k(const __bf16* __restrict__ qkv,
                                                 __bf16* __restrict__ outp) {
    __shared__ alignas(16) __bf16 VtF[2][64 * 128];   // [dv][pi-key], swizzled; 32KB
    int bh = blockIdx.x;
    int b = bh >> 4, h = bh & 15;
    int qbA = blockIdx.y;            // 0..15
    int qbB = 31 - qbA;
    int tid = threadIdx.x, lane = tid & 63, w = tid >> 6;
    int lq = lane & 15, g = lane >> 4;
    int qr0A = qbA * 64 + w * 16, qr0B = qbB * 64 + w * 16;
    size_t tokb = (size_t)b * SEQ;
    int lastA = qbA >> 1;            // A's last 128-key tile
    int nkbB = (qbB >> 1) + 1;       // B's 128-key tile count

    // V staging: lane owns in-tile keys {lane, lane+64}
    int vslotA = ((lane >> 5) << 2) + ((lane >> 2) & 3);   // 0..7
    int vkeA   = (((lane >> 4) & 1) << 2) + (lane & 3);    // 0..7
    int vslotB = vslotA + 8;                               // key lane+64 -> 8..15

    bf16x8 ones8;
#pragma unroll
    for (int e = 0; e < 8; ++e) ones8[e] = (__bf16)1.0f;

    bf16x8 aqA[2], aqB[2];
#pragma unroll
    for (int ks = 0; ks < 2; ++ks) {
        aqA[ks] = *(const bf16x8*)&qkv[(tokb + qr0A + lq) * QKVN + h * 64 + ks * 32 + g * 8];
        aqB[ks] = *(const bf16x8*)&qkv[(tokb + qr0B + lq) * QKVN + h * 64 + ks * 32 + g * 8];
    }

    bf16x8 kf[8][2];                 // K fragments in registers (64 VGPR)
    f32x4 oaA[4] = {}, oaB[4] = {};
    f32x4 olA = {}, olB = {};        // l accumulators (ones-MFMA)
    uint4 va0, va1, vb0, vb1;
    int cur = 0;

#define LOAD_K(kbn)                                                                                \
    _Pragma("unroll")                                                                              \
    for (int jt = 0; jt < 8; ++jt)                                                                 \
        _Pragma("unroll")                                                                          \
        for (int ks = 0; ks < 2; ++ks)                                                             \
            kf[jt][ks] = *(const bf16x8*)&qkv[(tokb + (kbn) * 128 + jt * 16 + lq) * QKVN + 1024    \
                                              + h * 64 + ks * 32 + g * 8];

#define LOAD_V(kbn)                                                                                \
    {                                                                                              \
        const __bf16* v0p = &qkv[(tokb + (kbn) * 128 + lane) * QKVN + 2048 + h * 64];              \
        const __bf16* v1p = v0p + (size_t)64 * QKVN;                                               \
        va0 = *(const uint4*)(v0p + (w * 2) * 8);                                                  \
        va1 = *(const uint4*)(v0p + (w * 2 + 1) * 8);                                              \
        vb0 = *(const uint4*)(v1p + (w * 2) * 8);                                                  \
        vb1 = *(const uint4*)(v1p + (w * 2 + 1) * 8);                                              \
    }

#define WRITE_V(buf)                                                                  \
    {                                                                                 \
        const __bf16* ea0 = (const __bf16*)&va0;                                      \
        const __bf16* ea1 = (const __bf16*)&va1;                                      \
        const __bf16* eb0 = (const __bf16*)&vb0;                                      \
        const __bf16* eb1 = (const __bf16*)&vb1;                                      \
        _Pragma("unroll")                                                             \
        for (int j = 0; j < 8; ++j) {                                                 \
            int dv0 = (w * 2) * 8 + j, dv1 = (w * 2 + 1) * 8 + j;                     \
            VtF[buf][dv0 * 128 + ((vslotA ^ j) << 3) + vkeA] = ea0[j];                \
            VtF[buf][dv1 * 128 + ((vslotA ^ j) << 3) + vkeA] = ea1[j];                \
            VtF[buf][dv0 * 128 + ((vslotB ^ j) << 3) + vkeA] = eb0[j];                \
            VtF[buf][dv1 * 128 + ((vslotB ^ j) << 3) + vkeA] = eb1[j];                \
        }                                                                             \
    }

#define QK_R(sc, aq)                                                                               \
    {                                                                                              \
        __builtin_amdgcn_s_setprio(1);                                                             \
        _Pragma("unroll")                                                                          \
        for (int jt = 0; jt < 8; ++jt)                                                             \
            _Pragma("unroll")                                                                      \
            for (int ks = 0; ks < 2; ++ks)                                                         \
                sc[jt] = __builtin_amdgcn_mfma_f32_16x16x32_bf16(kf[jt][ks], aq[ks], sc[jt], 0, 0, 0); \
        __builtin_amdgcn_s_setprio(0);                                                             \
    }

#define MASK_ONE(sc, qr0_t, kb_t)                                                                  \
    {                                                                                              \
        int qabs = (qr0_t) + lq;                                                                   \
        _Pragma("unroll")                                                                          \
        for (int jt = 0; jt < 8; ++jt)                                                             \
            _Pragma("unroll")                                                                      \
            for (int r = 0; r < 4; ++r) {                                                          \
                int key = (kb_t) * 128 + jt * 16 + g * 4 + r;                                      \
                if (key > qabs) sc[jt][r] = -1e9f;                                                 \
            }                                                                                      \
    }

#define EXP_ONE(sc)                                                                                \
    _Pragma("unroll")                                                                              \
    for (int jt = 0; jt < 8; ++jt)                                                                 \
        _Pragma("unroll")                                                                          \
        for (int r = 0; r < 4; ++r) sc[jt][r] = EXP2(sc[jt][r]);

#define PV_ONE(sc, oa, ol)                                                                         \
    {                                                                                              \
        __builtin_amdgcn_s_setprio(1);                                                             \
        _Pragma("unroll")                                                                          \
        for (int ks2 = 0; ks2 < 4; ++ks2) {                                                        \
            bf16x8 pfv;                                                                            \
            _Pragma("unroll")                                                                      \
            for (int e = 0; e < 4; ++e) {                                                          \
                pfv[e]     = (__bf16)sc[2 * ks2][e];                                               \
                pfv[e + 4] = (__bf16)sc[2 * ks2 + 1][e];                                           \
            }                                                                                      \
            ol = __builtin_amdgcn_mfma_f32_16x16x32_bf16(ones8, pfv, ol, 0, 0, 0);                 \
            _Pragma("unroll")                                                                      \
            for (int dt = 0; dt < 4; ++dt) {                                                       \
                bf16x8 av = *(const bf16x8*)&VtF[cur][(dt * 16 + lq) * 128 + (((ks2 * 4 + g) ^ (lq & 7)) << 3)]; \
                oa[dt] = __builtin_amdgcn_mfma_f32_16x16x32_bf16(av, pfv, oa[dt], 0, 0, 0);        \
            }                                                                                      \
        }                                                                                          \
        __builtin_amdgcn_s_setprio(0);                                                             \
    }

    // ---- prologue: K(0) -> regs, V(0) -> LDS buf 0 ----
    LOAD_K(0);
    LOAD_V(0);
    WRITE_V(0);
    asm volatile("s_waitcnt lgkmcnt(0)" ::: "memory");
    __builtin_amdgcn_s_barrier();
    __builtin_amdgcn_sched_barrier(0);

    for (int kb = 0; kb < nkbB; ++kb) {
        bool pf = (kb + 1) < nkbB;
        if (pf) LOAD_V(kb + 1);
        // tile B (always active)
        {
            f32x4 sc[8] = {};
            QK_R(sc, aqB);
            if (kb == nkbB - 1) MASK_ONE(sc, qr0B, kb);
            EXP_ONE(sc);
            PV_ONE(sc, oaB, olB);
        }
        // tile A (active while kb <= lastA) — reuses kf regs (K shared)
        if (kb <= lastA) {
            f32x4 sc[8] = {};
            QK_R(sc, aqA);
            if (kb == lastA) MASK_ONE(sc, qr0A, kb);
            EXP_ONE(sc);
            PV_ONE(sc, oaA, olA);
        }
        if (pf) {
            LOAD_K(kb + 1);          // overwrites kf after last use; latency spans barrier
            WRITE_V(cur ^ 1);
        }
        asm volatile("s_waitcnt lgkmcnt(0)" ::: "memory");
        __builtin_amdgcn_s_barrier();
        __builtin_amdgcn_sched_barrier(0);
        cur ^= 1;
    }

    // epilogue: l summed per-q by the ones-MFMA (no cross-lane ops)
    float invA = 1.0f / olA[0], invB = 1.0f / olB[0];
#pragma unroll
    for (int dt = 0; dt < 4; ++dt) {
        bf16x4 ovA, ovB;
#pragma unroll
        for (int r = 0; r < 4; ++r) {
            ovA[r] = (__bf16)(oaA[dt][r] * invA);
            ovB[r] = (__bf16)(oaB[dt][r] * invB);
        }
        *(bf16x4*)&outp[(tokb + qr0A + lq) * 1024 + h * 64 + dt * 16 + g * 4] = ovA;
        *(bf16x4*)&outp[(tokb + qr0B + lq) * 1024 + h * 64 + dt * 16 + g * 4] = ovB;
    }
#undef LOAD_K
#undef LOAD_V
#undef WRITE_V
#undef QK_R
#undef MASK_ONE
#undef EXP_ONE
#undef PV_ONE
}

// ---------------- launch ----------------
extern "C" void kernel_launch(void* const* d_in, const int* in_sizes, int n_in,
                              void* d_out, int out_size, void* d_ws, size_t ws_size,
                              hipStream_t stream) {
    const float* x       = (const float*)d_in[0];
    const float* cosv    = (const float*)d_in[1];
    const float* sinv    = (const float*)d_in[2];
    const float* wq      = (const float*)d_in[4];
    const float* wk      = (const float*)d_in[5];
    const float* wv      = (const float*)d_in[6];
    const float* wo      = (const float*)d_in[7];
    const float* wgate   = (const float*)d_in[8];
    const float* wup     = (const float*)d_in[9];
    const float* wdown   = (const float*)d_in[10];
    const float* norm1   = (const float*)d_in[11];
    const float* norm2   = (const float*)d_in[12];
    const float* ls_attn = (const float*)d_in[13];
    const float* ls_mlp  = (const float*)d_in[14];

    char* ws = (char*)d_ws;
    __bf16* wqkvT = (__bf16*)(ws + OFF_WQKVT);
    __bf16* woT   = (__bf16*)(ws + OFF_WOT);
    __bf16* wguT  = (__bf16*)(ws + OFF_WGUT);
    __bf16* wdT   = (__bf16*)(ws + OFF_WDT);
    __bf16* hb    = (__bf16*)(ws + OFF_HB);
    __bf16* qkvb  = (__bf16*)(ws + OFF_QKV);
    __bf16* attnb = (__bf16*)(ws + OFF_ATTN);
    float*  h2    = (float*)(ws + OFF_H2);
    __bf16* gb    = (__bf16*)(ws + OFF_G);
    __bf16* mb    = (__bf16*)(ws + OFF_M);
    float*  outf  = (float*)d_out;

    prep_k<<<7680, 256, 0, stream>>>(
        wq, wk, wv, wo, wgate, wup, wdown, wqkvT, woT, wguT, wdT, x, norm1, hb);
    gemm_bt<1, 128, 128, 64><<<dim3(QKVN / 128, NTOK / 128), 256, 0, stream>>>(
        hb, wqkvT, NTOK, QKVN, 512, qkvb, nullptr, nullptr, nullptr, cosv, sinv);
    attn_k<<<dim3(NB * NHEAD, 16), 256, 0, stream>>>(qkvb, attnb);
    gemm_bt<2, 64, 64, 128><<<dim3(HIDD / 64, NTOK / 64), 256, 0, stream>>>(
        attnb, woT, NTOK, HIDD, 1024, nullptr, h2, x, ls_attn, nullptr, nullptr);
    rmsnorm_k<<<NTOK, 256, 0, stream>>>(h2, norm2, gb);
    gemm_bt<3, 128, 128, 64><<<dim3(GUN / 128, NTOK / 128), 256, 0, stream>>>(
        gb, wguT, NTOK, GUN, 512, mb, nullptr, nullptr, nullptr, nullptr, nullptr);
    gemm_bt<2, 64, 64, 128><<<dim3(HIDD / 64, NTOK / 64), 256, 0, stream>>>(
        mb, wdT, NTOK, HIDD, 1024, nullptr, outf, h2, ls_mlp, nullptr, nullptr);
}

// Round 12
// 130.016 us; speedup vs baseline: 1.2029x; 1.2029x over previous
//
#include <hip/hip_runtime.h>
#include <hip/hip_bf16.h>

typedef __bf16 bf16x8 __attribute__((ext_vector_type(8)));
typedef __bf16 bf16x4 __attribute__((ext_vector_type(4)));
typedef float f32x4 __attribute__((ext_vector_type(4)));

#define SEQ   2048
#define NB    2
#define NTOK  4096
#define HIDD  512
#define NHEAD 16
#define DHEAD 64
#define QKVN  3072
#define GUN   2048

// workspace layout (bytes)
#define OFF_WQKVT  0u
#define OFF_WOT    3145728u
#define OFF_WGUT   4194304u
#define OFF_WDT    6291456u
#define OFF_HB     7340032u
#define OFF_QKV    11534336u
#define OFF_ATTN   36700160u
#define OFF_H2     45088768u
#define OFF_G      53477376u
#define OFF_M      (OFF_QKV + 16777216u)

#define QSCALE 0.1803368801111731f           // 0.125 * log2(e): exp2-domain scores

#if __has_builtin(__builtin_amdgcn_exp2f)
#define EXP2(x) __builtin_amdgcn_exp2f(x)
#else
#define EXP2(x) exp2f(x)
#endif

typedef unsigned int __attribute__((address_space(1))) as1_uint;
typedef unsigned int __attribute__((address_space(3))) as3_uint;
__device__ __forceinline__ void gload16(const void* g, void* l) {
    __builtin_amdgcn_global_load_lds((const as1_uint*)g, (as3_uint*)l, 16, 0, 0);
}

// ---------------- fused prep: 7 weight transposes + rmsnorm1, one launch ----
__global__ __launch_bounds__(256) void prep_k(
    const float* __restrict__ wq, const float* __restrict__ wk,
    const float* __restrict__ wv, const float* __restrict__ wo,
    const float* __restrict__ wg, const float* __restrict__ wu,
    const float* __restrict__ wd,
    __bf16* __restrict__ qkvT, __bf16* __restrict__ woT,
    __bf16* __restrict__ wguT, __bf16* __restrict__ wdT,
    const float* __restrict__ x, const float* __restrict__ norm1,
    __bf16* __restrict__ hb) {
    __shared__ float t[32][33];
    int bid = blockIdx.x;
    if (bid < 3584) {
        int which = bid >> 9, bx = bid & 511;
        const float* in; __bf16* out; int K, N, mode = 0, phase = 0;
        switch (which) {
            case 0: in = wq; out = qkvT;              K = 512;  N = 1024; break;
            case 1: in = wk; out = qkvT + 1024 * 512; K = 512;  N = 1024; break;
            case 2: in = wv; out = qkvT + 2048 * 512; K = 512;  N = 1024; break;
            case 3: in = wo; out = woT;               K = 1024; N = 512;  break;
            case 4: in = wg; out = wguT;              K = 512;  N = 1024; mode = 1; phase = 0; break;
            case 5: in = wu; out = wguT;              K = 512;  N = 1024; mode = 1; phase = 1; break;
            default: in = wd; out = wdT;              K = 1024; N = 512;  break;
        }
        int ntn = N >> 5;
        int n0 = (bx & (ntn - 1)) * 32;
        int k0 = (bx / ntn) * 32;
        int tx = threadIdx.x & 31, ty = threadIdx.x >> 5;
#pragma unroll
        for (int j = 0; j < 4; ++j)
            t[ty * 4 + j][tx] = in[(size_t)(k0 + ty * 4 + j) * N + n0 + tx];
        __syncthreads();
#pragma unroll
        for (int j = 0; j < 4; ++j) {
            int n = n0 + ty * 4 + j;
            int row = mode ? (((n >> 4) << 5) + phase * 16 + (n & 15)) : n;
            out[(size_t)row * K + k0 + tx] = (__bf16)t[tx][ty * 4 + j];
        }
    } else {
        int row = bid - 3584;
        int tt = threadIdx.x;
        const float* xr = x + (size_t)row * HIDD;
        float2 v = *(const float2*)&xr[tt * 2];
        float ss = v.x * v.x + v.y * v.y;
#pragma unroll
        for (int off = 32; off >= 1; off >>= 1) ss += __shfl_xor(ss, off);
        if ((tt & 63) == 0) t[0][tt >> 6] = ss;
        __syncthreads();
        float tot = t[0][0] + t[0][1] + t[0][2] + t[0][3];
        float r = rsqrtf(tot * (1.0f / HIDD) + 1e-8f);
        hb[(size_t)row * HIDD + tt * 2]     = (__bf16)(v.x * r * norm1[tt * 2]);
        hb[(size_t)row * HIDD + tt * 2 + 1] = (__bf16)(v.y * r * norm1[tt * 2 + 1]);
    }
}

// ---------------- RMSNorm (standalone, for norm2) ----------------
__global__ __launch_bounds__(256) void rmsnorm_k(const float* __restrict__ x,
                                                 const float* __restrict__ w,
                                                 __bf16* __restrict__ out) {
    int row = blockIdx.x;
    int t = threadIdx.x;
    const float* xr = x + (size_t)row * HIDD;
    float2 v = *(const float2*)&xr[t * 2];
    float ss = v.x * v.x + v.y * v.y;
#pragma unroll
    for (int off = 32; off >= 1; off >>= 1) ss += __shfl_xor(ss, off);
    __shared__ float red[4];
    if ((t & 63) == 0) red[t >> 6] = ss;
    __syncthreads();
    float tot = red[0] + red[1] + red[2] + red[3];
    float r = rsqrtf(tot * (1.0f / HIDD) + 1e-8f);
    out[(size_t)row * HIDD + t * 2]     = (__bf16)(v.x * r * w[t * 2]);
    out[(size_t)row * HIDD + t * 2 + 1] = (__bf16)(v.y * r * w[t * 2 + 1]);
}

// ---------------- GEMM: C[M][N] = A[M][K] * Bt[N][K]^T ----------------
// BK template param; XOR source-swizzled LDS (conflict-free ds_read_b128).
template <int EPI, int TM, int TN, int BK>
__global__ __launch_bounds__(256) void gemm_bt(const __bf16* __restrict__ A,
                                               const __bf16* __restrict__ Bt,
                                               int M, int N, int K,
                                               __bf16* __restrict__ Cb,
                                               float* __restrict__ Cf,
                                               const float* __restrict__ resid,
                                               const float* __restrict__ scale,
                                               const float* __restrict__ cosv,
                                               const float* __restrict__ sinv) {
    __shared__ alignas(16) __bf16 As[TM][BK];
    __shared__ alignas(16) __bf16 Bs[TN][BK];
    constexpr int MI = TM / 32, NI = TN / 32;
    constexpr int CPB = BK / 8;          // 16B chunks per row
    int m0 = blockIdx.y * TM, n0 = blockIdx.x * TN;
    int tid = threadIdx.x;
    int lane = tid & 63, w = tid >> 6;
    int wm = (w >> 1) * (TM / 2), wn = (w & 1) * (TN / 2);
    int lr = lane & 15, lkg = lane >> 4;
    f32x4 acc[MI][NI] = {};
    int nkt = K / BK;
    for (int kt = 0; kt < nkt; ++kt) {
        __syncthreads();
#pragma unroll
        for (int i = 0; i < (TM * BK) / 2048; ++i) {
            int c = i * 256 + tid;
            int row = c / CPB, ch = c % CPB;
            gload16(&A[(size_t)(m0 + row) * K + kt * BK + ((ch ^ (row & 7)) << 3)],
                    (__bf16*)As + c * 8);
        }
#pragma unroll
        for (int i = 0; i < (TN * BK) / 2048; ++i) {
            int c = i * 256 + tid;
            int row = c / CPB, ch = c % CPB;
            gload16(&Bt[(size_t)(n0 + row) * K + kt * BK + ((ch ^ (row & 7)) << 3)],
                    (__bf16*)Bs + c * 8);
        }
        __syncthreads();
#pragma unroll
        for (int kk = 0; kk < BK / 32; ++kk) {
            bf16x8 af[MI], bfv[NI];
#pragma unroll
            for (int mi = 0; mi < MI; ++mi) {
                int row = wm + mi * 16 + lr;
                af[mi] = *(const bf16x8*)&As[row][(((kk * 4 + lkg) ^ (row & 7)) << 3)];
            }
#pragma unroll
            for (int ni = 0; ni < NI; ++ni) {
                int row = wn + ni * 16 + lr;
                bfv[ni] = *(const bf16x8*)&Bs[row][(((kk * 4 + lkg) ^ (row & 7)) << 3)];
            }
#pragma unroll
            for (int mi = 0; mi < MI; ++mi)
#pragma unroll
                for (int ni = 0; ni < NI; ++ni)
                    acc[mi][ni] = __builtin_amdgcn_mfma_f32_16x16x32_bf16(
                        af[mi], bfv[ni], acc[mi][ni], 0, 0, 0);
        }
    }
    if (EPI == 1) {
        bool do_rope = (n0 + wn) < 2048;
        float qf = (n0 + wn) < 1024 ? QSCALE : 1.0f;
#pragma unroll
        for (int mi = 0; mi < MI; ++mi)
#pragma unroll
            for (int r = 0; r < 4; ++r) {
                int row = m0 + wm + mi * 16 + (lane >> 4) * 4 + r;
                int s = row & (SEQ - 1);
#pragma unroll
                for (int ni = 0; ni < 2; ++ni) {
                    float v1 = acc[mi][ni][r], v2 = acc[mi][ni + 2][r];
                    size_t i1 = (size_t)row * N + n0 + wn + ni * 16 + lr;
                    size_t i2 = i1 + 32;
                    if (do_rope) {
                        int d = ni * 16 + lr;
                        float c = cosv[s * 32 + d], sn = sinv[s * 32 + d];
                        Cb[i1] = (__bf16)((v1 * c - v2 * sn) * qf);
                        Cb[i2] = (__bf16)((v2 * c + v1 * sn) * qf);
                    } else {
                        Cb[i1] = (__bf16)v1;
                        Cb[i2] = (__bf16)v2;
                    }
                }
            }
    } else if (EPI == 3) {
#pragma unroll
        for (int mi = 0; mi < MI; ++mi)
#pragma unroll
            for (int r = 0; r < 4; ++r) {
                int row = m0 + wm + mi * 16 + (lane >> 4) * 4 + r;
#pragma unroll
                for (int ni = 0; ni < 4; ni += 2) {
                    float g = acc[mi][ni][r], u = acc[mi][ni + 1][r];
                    float mv = (g / (1.0f + __expf(-g))) * u;
                    int j = (((n0 + wn + ni * 16) >> 5) << 4) + lr;
                    Cb[(size_t)row * 1024 + j] = (__bf16)mv;
                }
            }
    } else {
#pragma unroll
        for (int mi = 0; mi < MI; ++mi)
#pragma unroll
            for (int ni = 0; ni < NI; ++ni)
#pragma unroll
                for (int r = 0; r < 4; ++r) {
                    int row = m0 + wm + mi * 16 + (lane >> 4) * 4 + r;
                    int col = n0 + wn + ni * 16 + lr;
                    size_t idx = (size_t)row * N + col;
                    float vv = acc[mi][ni][r];
                    if (EPI == 0) Cb[idx] = (__bf16)vv;
                    else          Cf[idx] = resid[idx] + vv * scale[col];
                }
    }
}

// ---------------- causal flash attention: paired q-tiles + D-half split ----------------
// r11 verdict: latency-bound at 2 waves/SIMD (grid 512 = 2 blocks/CU cap).
// Split each pair-block along output D: block (bh, pair, dh) computes only
// dv in [dh*32, dh*32+32). Grid 1024, LDS 24KB (K dbuf 16K + V-half 8K) ->
// 4 blocks/CU = 4 waves/SIMD (2x). QK+exp duplicated across halves (both
// pipes <25% busy - pure slack); K staged twice (+6MB L2, cheap).
// Balanced p-mapping: each CU's 4 blocks sum to a constant 98 iterations.
// KVBLK=64, no-max exp2 softmax, l via ones-MFMA, P in registers.
__global__ __launch_bounds__(256, 4) void attn_k(const __bf16* __restrict__ qkv,
                                                 __bf16* __restrict__ outp) {
    __shared__ alignas(16) __bf16 KtF[2][64 * 64];   // [key][d] swizzled, 16KB
    __shared__ alignas(16) __bf16 VtF[2][32 * 64];   // [dv-half][pi-key] swizzled, 8KB
    int bh = blockIdx.x;
    int b = bh >> 4, h = bh & 15;
    int yy = blockIdx.y;
    int dh = yy >> 4;                    // D-half: 0 -> dv 0..31, 1 -> dv 32..63
    int t16 = yy & 15;
    int qbA = (t16 < 8) ? t16 : (23 - t16);  // balanced pair mapping
    int qbB = 31 - qbA;
    int tid = threadIdx.x, lane = tid & 63, w = tid >> 6;
    int lq = lane & 15, g = lane >> 4;
    int qr0A = qbA * 64 + w * 16, qr0B = qbB * 64 + w * 16;
    size_t tokb = (size_t)b * SEQ;
    int nkb = qbB + 1;

    // V staging: thread covers key = tid&63, dv chunk c = tid>>6 (8 dv elems)
    int vkey = tid & 63, vc = tid >> 6;
    int vkslot = vkey >> 3, vke = vkey & 7;

    bf16x8 ones8;
#pragma unroll
    for (int e = 0; e < 8; ++e) ones8[e] = (__bf16)1.0f;

    bf16x8 aqA[2], aqB[2];
#pragma unroll
    for (int ks = 0; ks < 2; ++ks) {
        aqA[ks] = *(const bf16x8*)&qkv[(tokb + qr0A + lq) * QKVN + h * 64 + ks * 32 + g * 8];
        aqB[ks] = *(const bf16x8*)&qkv[(tokb + qr0B + lq) * QKVN + h * 64 + ks * 32 + g * 8];
    }

    f32x4 oaA[2] = {}, oaB[2] = {};      // dv-half: 2 x 16 output dims
    f32x4 olA = {}, olB = {};            // l accumulators (ones-MFMA)
    uint4 vv;
    int cur = 0;

#define STAGE_K(kbn, buf)                                                                          \
    {                                                                                              \
        _Pragma("unroll")                                                                          \
        for (int i = 0; i < 2; ++i) {                                                              \
            int c = i * 256 + tid;                                                                 \
            int kr = c >> 3, sw = c & 7;                                                           \
            gload16(&qkv[(tokb + (kbn) * 64 + kr) * QKVN + 1024 + h * 64 + ((sw ^ (kr & 7)) << 3)], \
                    &KtF[buf][c * 8]);                                                             \
        }                                                                                          \
    }

#define LOAD_V(kbn)                                                                                \
    vv = *(const uint4*)&qkv[(tokb + (kbn) * 64 + vkey) * QKVN + 2048 + h * 64 + dh * 32 + vc * 8];

#define WRITE_V(buf)                                                                  \
    {                                                                                 \
        const __bf16* ve = (const __bf16*)&vv;                                        \
        _Pragma("unroll")                                                             \
        for (int j = 0; j < 8; ++j) {                                                 \
            int dv = vc * 8 + j;     /* dv & 7 == j */                                \
            VtF[buf][dv * 64 + ((vkslot ^ j) << 3) + vke] = ve[j];                    \
        }                                                                             \
    }

#define QK_ONE(sc, aq)                                                                             \
    {                                                                                              \
        __builtin_amdgcn_s_setprio(1);                                                             \
        _Pragma("unroll")                                                                          \
        for (int jt = 0; jt < 4; ++jt)                                                             \
            _Pragma("unroll")                                                                      \
            for (int ks = 0; ks < 2; ++ks) {                                                       \
                bf16x8 bk = *(const bf16x8*)&KtF[cur][(jt * 16 + lq) * 64 + (((ks * 4 + g) ^ (lq & 7)) << 3)]; \
                sc[jt] = __builtin_amdgcn_mfma_f32_16x16x32_bf16(bk, aq[ks], sc[jt], 0, 0, 0);     \
            }                                                                                      \
        __builtin_amdgcn_s_setprio(0);                                                             \
    }

#define MASK_ONE(sc, qr0_t, kb_t)                                                                  \
    {                                                                                              \
        int qabs = (qr0_t) + lq;                                                                   \
        _Pragma("unroll")                                                                          \
        for (int jt = 0; jt < 4; ++jt)                                                             \
            _Pragma("unroll")                                                                      \
            for (int r = 0; r < 4; ++r) {                                                          \
                int key = (kb_t) * 64 + jt * 16 + g * 4 + r;                                       \
                if (key > qabs) sc[jt][r] = -1e9f;                                                 \
            }                                                                                      \
    }

#define EXP_ONE(sc)                                                                                \
    _Pragma("unroll")                                                                              \
    for (int jt = 0; jt < 4; ++jt)                                                                 \
        _Pragma("unroll")                                                                          \
        for (int r = 0; r < 4; ++r) sc[jt][r] = EXP2(sc[jt][r]);

#define PV_ONE(sc, oa, ol)                                                                         \
    {                                                                                              \
        __builtin_amdgcn_s_setprio(1);                                                             \
        _Pragma("unroll")                                                                          \
        for (int ks2 = 0; ks2 < 2; ++ks2) {                                                        \
            bf16x8 pfv;                                                                            \
            _Pragma("unroll")                                                                      \
            for (int e = 0; e < 4; ++e) {                                                          \
                pfv[e]     = (__bf16)sc[2 * ks2][e];                                               \
                pfv[e + 4] = (__bf16)sc[2 * ks2 + 1][e];                                           \
            }                                                                                      \
            ol = __builtin_amdgcn_mfma_f32_16x16x32_bf16(ones8, pfv, ol, 0, 0, 0);                 \
            _Pragma("unroll")                                                                      \
            for (int dt = 0; dt < 2; ++dt) {                                                       \
                int row = dt * 16 + lq;                                                            \
                bf16x8 av = *(const bf16x8*)&VtF[cur][row * 64 + (((ks2 * 4 + g) ^ (row & 7)) << 3)]; \
                oa[dt] = __builtin_amdgcn_mfma_f32_16x16x32_bf16(av, pfv, oa[dt], 0, 0, 0);        \
            }                                                                                      \
        }                                                                                          \
        __builtin_amdgcn_s_setprio(0);                                                             \
    }

    // ---- prologue: stage tile 0 into buf 0 ----
    STAGE_K(0, 0);
    LOAD_V(0);
    WRITE_V(0);
    __syncthreads();

    for (int kb = 0; kb < nkb; ++kb) {
        bool pf = (kb + 1) < nkb;
        if (pf) {                        // issue next tile's loads early
            STAGE_K(kb + 1, cur ^ 1);
            LOAD_V(kb + 1);
        }
        // tile B (always active)
        {
            f32x4 sc[4] = {};
            QK_ONE(sc, aqB);
            if (kb == qbB) MASK_ONE(sc, qr0B, kb);
            EXP_ONE(sc);
            PV_ONE(sc, oaB, olB);
        }
        // tile A (active while kb <= qbA); reuses sc registers
        if (kb <= qbA) {
            f32x4 sc[4] = {};
            QK_ONE(sc, aqA);
            if (kb == qbA) MASK_ONE(sc, qr0A, kb);
            EXP_ONE(sc);
            PV_ONE(sc, oaA, olA);
        }
        if (pf) WRITE_V(cur ^ 1);
        __syncthreads();
        cur ^= 1;
    }

    // epilogue: l summed per-q by the ones-MFMA; write this block's dv half
    float invA = 1.0f / olA[0], invB = 1.0f / olB[0];
#pragma unroll
    for (int dt = 0; dt < 2; ++dt) {
        bf16x4 ovA, ovB;
#pragma unroll
        for (int r = 0; r < 4; ++r) {
            ovA[r] = (__bf16)(oaA[dt][r] * invA);
            ovB[r] = (__bf16)(oaB[dt][r] * invB);
        }
        *(bf16x4*)&outp[(tokb + qr0A + lq) * 1024 + h * 64 + dh * 32 + dt * 16 + g * 4] = ovA;
        *(bf16x4*)&outp[(tokb + qr0B + lq) * 1024 + h * 64 + dh * 32 + dt * 16 + g * 4] = ovB;
    }
#undef STAGE_K
#undef LOAD_V
#undef WRITE_V
#undef QK_ONE
#undef MASK_ONE
#undef EXP_ONE
#undef PV_ONE
}

// ---------------- launch ----------------
extern "C" void kernel_launch(void* const* d_in, const int* in_sizes, int n_in,
                              void* d_out, int out_size, void* d_ws, size_t ws_size,
                              hipStream_t stream) {
    const float* x       = (const float*)d_in[0];
    const float* cosv    = (const float*)d_in[1];
    const float* sinv    = (const float*)d_in[2];
    const float* wq      = (const float*)d_in[4];
    const float* wk      = (const float*)d_in[5];
    const float* wv      = (const float*)d_in[6];
    const float* wo      = (const float*)d_in[7];
    const float* wgate   = (const float*)d_in[8];
    const float* wup     = (const float*)d_in[9];
    const float* wdown   = (const float*)d_in[10];
    const float* norm1   = (const float*)d_in[11];
    const float* norm2   = (const float*)d_in[12];
    const float* ls_attn = (const float*)d_in[13];
    const float* ls_mlp  = (const float*)d_in[14];

    char* ws = (char*)d_ws;
    __bf16* wqkvT = (__bf16*)(ws + OFF_WQKVT);
    __bf16* woT   = (__bf16*)(ws + OFF_WOT);
    __bf16* wguT  = (__bf16*)(ws + OFF_WGUT);
    __bf16* wdT   = (__bf16*)(ws + OFF_WDT);
    __bf16* hb    = (__bf16*)(ws + OFF_HB);
    __bf16* qkvb  = (__bf16*)(ws + OFF_QKV);
    __bf16* attnb = (__bf16*)(ws + OFF_ATTN);
    float*  h2    = (float*)(ws + OFF_H2);
    __bf16* gb    = (__bf16*)(ws + OFF_G);
    __bf16* mb    = (__bf16*)(ws + OFF_M);
    float*  outf  = (float*)d_out;

    prep_k<<<7680, 256, 0, stream>>>(
        wq, wk, wv, wo, wgate, wup, wdown, wqkvT, woT, wguT, wdT, x, norm1, hb);
    gemm_bt<1, 128, 128, 64><<<dim3(QKVN / 128, NTOK / 128), 256, 0, stream>>>(
        hb, wqkvT, NTOK, QKVN, 512, qkvb, nullptr, nullptr, nullptr, cosv, sinv);
    attn_k<<<dim3(NB * NHEAD, 32), 256, 0, stream>>>(qkvb, attnb);
    gemm_bt<2, 64, 64, 128><<<dim3(HIDD / 64, NTOK / 64), 256, 0, stream>>>(
        attnb, woT, NTOK, HIDD, 1024, nullptr, h2, x, ls_attn, nullptr, nullptr);
    rmsnorm_k<<<NTOK, 256, 0, stream>>>(h2, norm2, gb);
    gemm_bt<3, 128, 128, 64><<<dim3(GUN / 128, NTOK / 128), 256, 0, stream>>>(
        gb, wguT, NTOK, GUN, 512, mb, nullptr, nullptr, nullptr, nullptr, nullptr);
    gemm_bt<2, 64, 64, 128><<<dim3(HIDD / 64, NTOK / 64), 256, 0, stream>>>(
        mb, wdT, NTOK, HIDD, 1024, nullptr, outf, h2, ls_mlp, nullptr, nullptr);
}

// Round 13
// 118.591 us; speedup vs baseline: 1.3188x; 1.0963x over previous
//
#include <hip/hip_runtime.h>
#include <hip/hip_bf16.h>

typedef __bf16 bf16x8 __attribute__((ext_vector_type(8)));
typedef __bf16 bf16x4 __attribute__((ext_vector_type(4)));
typedef float f32x4 __attribute__((ext_vector_type(4)));

#define SEQ   2048
#define NB    2
#define NTOK  4096
#define HIDD  512
#define NHEAD 16
#define DHEAD 64
#define QKVN  3072
#define GUN   2048

// workspace layout (bytes)
#define OFF_WQKVT  0u
#define OFF_WOT    3145728u
#define OFF_WGUT   4194304u
#define OFF_WDT    6291456u
#define OFF_HB     7340032u
#define OFF_QKV    11534336u
#define OFF_ATTN   36700160u
#define OFF_H2     45088768u
#define OFF_G      53477376u
#define OFF_M      (OFF_QKV + 16777216u)

#define QSCALE 0.1803368801111731f           // 0.125 * log2(e): exp2-domain scores

#if __has_builtin(__builtin_amdgcn_exp2f)
#define EXP2(x) __builtin_amdgcn_exp2f(x)
#else
#define EXP2(x) exp2f(x)
#endif

typedef unsigned int __attribute__((address_space(1))) as1_uint;
typedef unsigned int __attribute__((address_space(3))) as3_uint;
__device__ __forceinline__ void gload16(const void* g, void* l) {
    __builtin_amdgcn_global_load_lds((const as1_uint*)g, (as3_uint*)l, 16, 0, 0);
}

// ---------------- fused prep: 7 weight transposes + rmsnorm1, one launch ----
__global__ __launch_bounds__(256) void prep_k(
    const float* __restrict__ wq, const float* __restrict__ wk,
    const float* __restrict__ wv, const float* __restrict__ wo,
    const float* __restrict__ wg, const float* __restrict__ wu,
    const float* __restrict__ wd,
    __bf16* __restrict__ qkvT, __bf16* __restrict__ woT,
    __bf16* __restrict__ wguT, __bf16* __restrict__ wdT,
    const float* __restrict__ x, const float* __restrict__ norm1,
    __bf16* __restrict__ hb) {
    __shared__ float t[32][33];
    int bid = blockIdx.x;
    if (bid < 3584) {
        int which = bid >> 9, bx = bid & 511;
        const float* in; __bf16* out; int K, N, mode = 0, phase = 0;
        switch (which) {
            case 0: in = wq; out = qkvT;              K = 512;  N = 1024; break;
            case 1: in = wk; out = qkvT + 1024 * 512; K = 512;  N = 1024; break;
            case 2: in = wv; out = qkvT + 2048 * 512; K = 512;  N = 1024; break;
            case 3: in = wo; out = woT;               K = 1024; N = 512;  break;
            case 4: in = wg; out = wguT;              K = 512;  N = 1024; mode = 1; phase = 0; break;
            case 5: in = wu; out = wguT;              K = 512;  N = 1024; mode = 1; phase = 1; break;
            default: in = wd; out = wdT;              K = 1024; N = 512;  break;
        }
        int ntn = N >> 5;
        int n0 = (bx & (ntn - 1)) * 32;
        int k0 = (bx / ntn) * 32;
        int tx = threadIdx.x & 31, ty = threadIdx.x >> 5;
#pragma unroll
        for (int j = 0; j < 4; ++j)
            t[ty * 4 + j][tx] = in[(size_t)(k0 + ty * 4 + j) * N + n0 + tx];
        __syncthreads();
#pragma unroll
        for (int j = 0; j < 4; ++j) {
            int n = n0 + ty * 4 + j;
            int row = mode ? (((n >> 4) << 5) + phase * 16 + (n & 15)) : n;
            out[(size_t)row * K + k0 + tx] = (__bf16)t[tx][ty * 4 + j];
        }
    } else {
        int row = bid - 3584;
        int tt = threadIdx.x;
        const float* xr = x + (size_t)row * HIDD;
        float2 v = *(const float2*)&xr[tt * 2];
        float ss = v.x * v.x + v.y * v.y;
#pragma unroll
        for (int off = 32; off >= 1; off >>= 1) ss += __shfl_xor(ss, off);
        if ((tt & 63) == 0) t[0][tt >> 6] = ss;
        __syncthreads();
        float tot = t[0][0] + t[0][1] + t[0][2] + t[0][3];
        float r = rsqrtf(tot * (1.0f / HIDD) + 1e-8f);
        hb[(size_t)row * HIDD + tt * 2]     = (__bf16)(v.x * r * norm1[tt * 2]);
        hb[(size_t)row * HIDD + tt * 2 + 1] = (__bf16)(v.y * r * norm1[tt * 2 + 1]);
    }
}

// ---------------- RMSNorm (standalone, for norm2) ----------------
__global__ __launch_bounds__(256) void rmsnorm_k(const float* __restrict__ x,
                                                 const float* __restrict__ w,
                                                 __bf16* __restrict__ out) {
    int row = blockIdx.x;
    int t = threadIdx.x;
    const float* xr = x + (size_t)row * HIDD;
    float2 v = *(const float2*)&xr[t * 2];
    float ss = v.x * v.x + v.y * v.y;
#pragma unroll
    for (int off = 32; off >= 1; off >>= 1) ss += __shfl_xor(ss, off);
    __shared__ float red[4];
    if ((t & 63) == 0) red[t >> 6] = ss;
    __syncthreads();
    float tot = red[0] + red[1] + red[2] + red[3];
    float r = rsqrtf(tot * (1.0f / HIDD) + 1e-8f);
    out[(size_t)row * HIDD + t * 2]     = (__bf16)(v.x * r * w[t * 2]);
    out[(size_t)row * HIDD + t * 2 + 1] = (__bf16)(v.y * r * w[t * 2 + 1]);
}

// ---------------- GEMM: C[M][N] = A[M][K] * Bt[N][K]^T ----------------
// BK template param; XOR source-swizzled LDS; XCD-aware block swizzle (T1):
// same-XCD-consecutive blocks share the A row-panel -> panel L2 hits.
template <int EPI, int TM, int TN, int BK>
__global__ __launch_bounds__(256) void gemm_bt(const __bf16* __restrict__ A,
                                               const __bf16* __restrict__ Bt,
                                               int M, int N, int K,
                                               __bf16* __restrict__ Cb,
                                               float* __restrict__ Cf,
                                               const float* __restrict__ resid,
                                               const float* __restrict__ scale,
                                               const float* __restrict__ cosv,
                                               const float* __restrict__ sinv) {
    __shared__ alignas(16) __bf16 As[TM][BK];
    __shared__ alignas(16) __bf16 Bs[TN][BK];
    constexpr int MI = TM / 32, NI = TN / 32;
    constexpr int CPB = BK / 8;          // 16B chunks per row
    // XCD swizzle (grids here are all divisible by 8)
    int nwg = gridDim.x * gridDim.y;
    int bid = blockIdx.y * gridDim.x + blockIdx.x;
    int swz = (bid & 7) * (nwg >> 3) + (bid >> 3);
    int bx = swz % gridDim.x, by = swz / gridDim.x;
    int m0 = by * TM, n0 = bx * TN;
    int tid = threadIdx.x;
    int lane = tid & 63, w = tid >> 6;
    int wm = (w >> 1) * (TM / 2), wn = (w & 1) * (TN / 2);
    int lr = lane & 15, lkg = lane >> 4;
    f32x4 acc[MI][NI] = {};
    int nkt = K / BK;
    for (int kt = 0; kt < nkt; ++kt) {
        __syncthreads();
#pragma unroll
        for (int i = 0; i < (TM * BK) / 2048; ++i) {
            int c = i * 256 + tid;
            int row = c / CPB, ch = c % CPB;
            gload16(&A[(size_t)(m0 + row) * K + kt * BK + ((ch ^ (row & 7)) << 3)],
                    (__bf16*)As + c * 8);
        }
#pragma unroll
        for (int i = 0; i < (TN * BK) / 2048; ++i) {
            int c = i * 256 + tid;
            int row = c / CPB, ch = c % CPB;
            gload16(&Bt[(size_t)(n0 + row) * K + kt * BK + ((ch ^ (row & 7)) << 3)],
                    (__bf16*)Bs + c * 8);
        }
        __syncthreads();
#pragma unroll
        for (int kk = 0; kk < BK / 32; ++kk) {
            bf16x8 af[MI], bfv[NI];
#pragma unroll
            for (int mi = 0; mi < MI; ++mi) {
                int row = wm + mi * 16 + lr;
                af[mi] = *(const bf16x8*)&As[row][(((kk * 4 + lkg) ^ (row & 7)) << 3)];
            }
#pragma unroll
            for (int ni = 0; ni < NI; ++ni) {
                int row = wn + ni * 16 + lr;
                bfv[ni] = *(const bf16x8*)&Bs[row][(((kk * 4 + lkg) ^ (row & 7)) << 3)];
            }
#pragma unroll
            for (int mi = 0; mi < MI; ++mi)
#pragma unroll
                for (int ni = 0; ni < NI; ++ni)
                    acc[mi][ni] = __builtin_amdgcn_mfma_f32_16x16x32_bf16(
                        af[mi], bfv[ni], acc[mi][ni], 0, 0, 0);
        }
    }
    if (EPI == 1) {
        bool do_rope = (n0 + wn) < 2048;
        float qf = (n0 + wn) < 1024 ? QSCALE : 1.0f;
#pragma unroll
        for (int mi = 0; mi < MI; ++mi)
#pragma unroll
            for (int r = 0; r < 4; ++r) {
                int row = m0 + wm + mi * 16 + (lane >> 4) * 4 + r;
                int s = row & (SEQ - 1);
#pragma unroll
                for (int ni = 0; ni < 2; ++ni) {
                    float v1 = acc[mi][ni][r], v2 = acc[mi][ni + 2][r];
                    size_t i1 = (size_t)row * N + n0 + wn + ni * 16 + lr;
                    size_t i2 = i1 + 32;
                    if (do_rope) {
                        int d = ni * 16 + lr;
                        float c = cosv[s * 32 + d], sn = sinv[s * 32 + d];
                        Cb[i1] = (__bf16)((v1 * c - v2 * sn) * qf);
                        Cb[i2] = (__bf16)((v2 * c + v1 * sn) * qf);
                    } else {
                        Cb[i1] = (__bf16)v1;
                        Cb[i2] = (__bf16)v2;
                    }
                }
            }
    } else if (EPI == 3) {
#pragma unroll
        for (int mi = 0; mi < MI; ++mi)
#pragma unroll
            for (int r = 0; r < 4; ++r) {
                int row = m0 + wm + mi * 16 + (lane >> 4) * 4 + r;
#pragma unroll
                for (int ni = 0; ni < 4; ni += 2) {
                    float g = acc[mi][ni][r], u = acc[mi][ni + 1][r];
                    float mv = (g / (1.0f + __expf(-g))) * u;
                    int j = (((n0 + wn + ni * 16) >> 5) << 4) + lr;
                    Cb[(size_t)row * 1024 + j] = (__bf16)mv;
                }
            }
    } else {
#pragma unroll
        for (int mi = 0; mi < MI; ++mi)
#pragma unroll
            for (int ni = 0; ni < NI; ++ni)
#pragma unroll
                for (int r = 0; r < 4; ++r) {
                    int row = m0 + wm + mi * 16 + (lane >> 4) * 4 + r;
                    int col = n0 + wn + ni * 16 + lr;
                    size_t idx = (size_t)row * N + col;
                    float vv = acc[mi][ni][r];
                    if (EPI == 0) Cb[idx] = (__bf16)vv;
                    else          Cf[idx] = resid[idx] + vv * scale[col];
                }
    }
}

// ---------------- causal flash attention, paired q-tiles, KVBLK=128 ----------------
// r10 structure (best measured: 46.4us) + balanced pair mapping: block y and
// block y+8 (co-dispatched to the same CU slot modulo 256) get pairs whose
// iteration counts sum to a constant 25 -> uniform CU drain (r12 lesson:
// never buy occupancy with duplicated work; fix balance instead).
// No-max exp2 softmax, l via ones-MFMA, P in registers, dbuf K/V, 64KB LDS.
__global__ __launch_bounds__(256, 2) void attn_k(const __bf16* __restrict__ qkv,
                                                 __bf16* __restrict__ outp) {
    __shared__ alignas(16) __bf16 KtF[2][128 * 64];   // [key][d], source-swizzled
    __shared__ alignas(16) __bf16 VtF[2][64 * 128];   // [dv][pi-key], swizzled
    int bh = blockIdx.x;
    int b = bh >> 4, h = bh & 15;
    int yy = blockIdx.y;
    int qbA = (yy < 8) ? yy : (23 - yy);  // balanced: load(y)+load(y+8) = const
    int qbB = 31 - qbA;
    int tid = threadIdx.x, lane = tid & 63, w = tid >> 6;
    int lq = lane & 15, g = lane >> 4;
    int qr0A = qbA * 64 + w * 16, qr0B = qbB * 64 + w * 16;
    size_t tokb = (size_t)b * SEQ;
    int lastA = qbA >> 1;            // A's last 128-key tile
    int nkbB = (qbB >> 1) + 1;       // B's 128-key tile count

    // V staging: lane owns in-tile keys {lane, lane+64}
    int vslotA = ((lane >> 5) << 2) + ((lane >> 2) & 3);   // 0..7
    int vkeA   = (((lane >> 4) & 1) << 2) + (lane & 3);    // 0..7
    int vslotB = vslotA + 8;                               // key lane+64 -> 8..15

    bf16x8 ones8;
#pragma unroll
    for (int e = 0; e < 8; ++e) ones8[e] = (__bf16)1.0f;

    bf16x8 aqA[2], aqB[2];
#pragma unroll
    for (int ks = 0; ks < 2; ++ks) {
        aqA[ks] = *(const bf16x8*)&qkv[(tokb + qr0A + lq) * QKVN + h * 64 + ks * 32 + g * 8];
        aqB[ks] = *(const bf16x8*)&qkv[(tokb + qr0B + lq) * QKVN + h * 64 + ks * 32 + g * 8];
    }

    f32x4 oaA[4] = {}, oaB[4] = {};
    f32x4 olA = {}, olB = {};        // l accumulators (ones-MFMA)
    uint4 va0, va1, vb0, vb1;
    int cur = 0;

#define STAGE(kbn, buf)                                                                            \
    {                                                                                              \
        _Pragma("unroll")                                                                          \
        for (int i = 0; i < 4; ++i) {                                                              \
            int c = i * 256 + tid;                                                                 \
            int kr = c >> 3, sw = c & 7;                                                           \
            gload16(&qkv[(tokb + (kbn) * 128 + kr) * QKVN + 1024 + h * 64 + ((sw ^ (kr & 7)) << 3)], \
                    &KtF[buf][c * 8]);                                                             \
        }                                                                                          \
        const __bf16* v0p = &qkv[(tokb + (kbn) * 128 + lane) * QKVN + 2048 + h * 64];              \
        const __bf16* v1p = v0p + (size_t)64 * QKVN;                                               \
        va0 = *(const uint4*)(v0p + (w * 2) * 8);                                                  \
        va1 = *(const uint4*)(v0p + (w * 2 + 1) * 8);                                              \
        vb0 = *(const uint4*)(v1p + (w * 2) * 8);                                                  \
        vb1 = *(const uint4*)(v1p + (w * 2 + 1) * 8);                                              \
    }

#define WRITE_V(buf)                                                                  \
    {                                                                                 \
        const __bf16* ea0 = (const __bf16*)&va0;                                      \
        const __bf16* ea1 = (const __bf16*)&va1;                                      \
        const __bf16* eb0 = (const __bf16*)&vb0;                                      \
        const __bf16* eb1 = (const __bf16*)&vb1;                                      \
        _Pragma("unroll")                                                             \
        for (int j = 0; j < 8; ++j) {                                                 \
            int dv0 = (w * 2) * 8 + j, dv1 = (w * 2 + 1) * 8 + j;                     \
            VtF[buf][dv0 * 128 + ((vslotA ^ j) << 3) + vkeA] = ea0[j];                \
            VtF[buf][dv1 * 128 + ((vslotA ^ j) << 3) + vkeA] = ea1[j];                \
            VtF[buf][dv0 * 128 + ((vslotB ^ j) << 3) + vkeA] = eb0[j];                \
            VtF[buf][dv1 * 128 + ((vslotB ^ j) << 3) + vkeA] = eb1[j];                \
        }                                                                             \
    }

#define QK_ONE(sc, aq)                                                                             \
    _Pragma("unroll")                                                                              \
    for (int jt = 0; jt < 8; ++jt)                                                                 \
        _Pragma("unroll")                                                                          \
        for (int ks = 0; ks < 2; ++ks) {                                                           \
            bf16x8 bk = *(const bf16x8*)&KtF[cur][(jt * 16 + lq) * 64 + (((ks * 4 + g) ^ (lq & 7)) << 3)]; \
            sc[jt] = __builtin_amdgcn_mfma_f32_16x16x32_bf16(bk, aq[ks], sc[jt], 0, 0, 0);         \
        }

#define MASK_ONE(sc, qr0_t, kb_t)                                                                  \
    {                                                                                              \
        int qabs = (qr0_t) + lq;                                                                   \
        _Pragma("unroll")                                                                          \
        for (int jt = 0; jt < 8; ++jt)                                                             \
            _Pragma("unroll")                                                                      \
            for (int r = 0; r < 4; ++r) {                                                          \
                int key = (kb_t) * 128 + jt * 16 + g * 4 + r;                                      \
                if (key > qabs) sc[jt][r] = -1e9f;                                                 \
            }                                                                                      \
    }

#define EXP_ONE(sc)                                                                                \
    _Pragma("unroll")                                                                              \
    for (int jt = 0; jt < 8; ++jt)                                                                 \
        _Pragma("unroll")                                                                          \
        for (int r = 0; r < 4; ++r) sc[jt][r] = EXP2(sc[jt][r]);

#define PV_ONE(sc, oa, ol)                                                                         \
    _Pragma("unroll")                                                                              \
    for (int ks2 = 0; ks2 < 4; ++ks2) {                                                            \
        bf16x8 pfv;                                                                                \
        _Pragma("unroll")                                                                          \
        for (int e = 0; e < 4; ++e) {                                                              \
            pfv[e]     = (__bf16)sc[2 * ks2][e];                                                   \
            pfv[e + 4] = (__bf16)sc[2 * ks2 + 1][e];                                               \
        }                                                                                          \
        ol = __builtin_amdgcn_mfma_f32_16x16x32_bf16(ones8, pfv, ol, 0, 0, 0);                     \
        _Pragma("unroll")                                                                          \
        for (int dt = 0; dt < 4; ++dt) {                                                           \
            bf16x8 av = *(const bf16x8*)&VtF[cur][(dt * 16 + lq) * 128 + (((ks2 * 4 + g) ^ (lq & 7)) << 3)]; \
            oa[dt] = __builtin_amdgcn_mfma_f32_16x16x32_bf16(av, pfv, oa[dt], 0, 0, 0);            \
        }                                                                                          \
    }

    // ---- prologue: stage tile 0 into buf 0 ----
    STAGE(0, 0);
    WRITE_V(0);
    __syncthreads();

    // ---- phase 1: kb = 0..lastA — both tiles, shared K/V reads ----
    for (int kb = 0; kb <= lastA; ++kb) {
        STAGE(kb + 1, cur ^ 1);
        {
            f32x4 scA[8] = {}, scB[8] = {};
            __builtin_amdgcn_s_setprio(1);
#pragma unroll
            for (int jt = 0; jt < 8; ++jt)
#pragma unroll
                for (int ks = 0; ks < 2; ++ks) {
                    bf16x8 bk = *(const bf16x8*)&KtF[cur][(jt * 16 + lq) * 64 + (((ks * 4 + g) ^ (lq & 7)) << 3)];
                    scB[jt] = __builtin_amdgcn_mfma_f32_16x16x32_bf16(bk, aqB[ks], scB[jt], 0, 0, 0);
                    scA[jt] = __builtin_amdgcn_mfma_f32_16x16x32_bf16(bk, aqA[ks], scA[jt], 0, 0, 0);
                }
            __builtin_amdgcn_s_setprio(0);
            if (kb == lastA) MASK_ONE(scA, qr0A, kb);   // only A hits diagonal here
            EXP_ONE(scB);
            EXP_ONE(scA);
            __builtin_amdgcn_s_setprio(1);
#pragma unroll
            for (int ks2 = 0; ks2 < 4; ++ks2) {
                bf16x8 pfvA, pfvB;
#pragma unroll
                for (int e = 0; e < 4; ++e) {
                    pfvB[e]     = (__bf16)scB[2 * ks2][e];
                    pfvB[e + 4] = (__bf16)scB[2 * ks2 + 1][e];
                    pfvA[e]     = (__bf16)scA[2 * ks2][e];
                    pfvA[e + 4] = (__bf16)scA[2 * ks2 + 1][e];
                }
                olB = __builtin_amdgcn_mfma_f32_16x16x32_bf16(ones8, pfvB, olB, 0, 0, 0);
                olA = __builtin_amdgcn_mfma_f32_16x16x32_bf16(ones8, pfvA, olA, 0, 0, 0);
#pragma unroll
                for (int dt = 0; dt < 4; ++dt) {
                    bf16x8 av = *(const bf16x8*)&VtF[cur][(dt * 16 + lq) * 128 + (((ks2 * 4 + g) ^ (lq & 7)) << 3)];
                    oaB[dt] = __builtin_amdgcn_mfma_f32_16x16x32_bf16(av, pfvB, oaB[dt], 0, 0, 0);
                    oaA[dt] = __builtin_amdgcn_mfma_f32_16x16x32_bf16(av, pfvA, oaA[dt], 0, 0, 0);
                }
            }
            __builtin_amdgcn_s_setprio(0);
        }
        WRITE_V(cur ^ 1);
        __syncthreads();
        cur ^= 1;
    }
    // ---- phase 2: kb = lastA+1..nkbB-1 — tile B only ----
    for (int kb = lastA + 1; kb < nkbB; ++kb) {
        bool pf = (kb + 1) < nkbB;
        if (pf) STAGE(kb + 1, cur ^ 1);
        {
            f32x4 sc[8] = {};
            __builtin_amdgcn_s_setprio(1);
            QK_ONE(sc, aqB);
            __builtin_amdgcn_s_setprio(0);
            if (kb == (qbB >> 1)) MASK_ONE(sc, qr0B, kb);
            EXP_ONE(sc);
            __builtin_amdgcn_s_setprio(1);
            PV_ONE(sc, oaB, olB);
            __builtin_amdgcn_s_setprio(0);
        }
        if (pf) WRITE_V(cur ^ 1);
        __syncthreads();
        cur ^= 1;
    }

    // epilogue: l already summed per-q by the ones-MFMA (no shuffles)
    float invA = 1.0f / olA[0], invB = 1.0f / olB[0];
#pragma unroll
    for (int dt = 0; dt < 4; ++dt) {
        bf16x4 ovA, ovB;
#pragma unroll
        for (int r = 0; r < 4; ++r) {
            ovA[r] = (__bf16)(oaA[dt][r] * invA);
            ovB[r] = (__bf16)(oaB[dt][r] * invB);
        }
        *(bf16x4*)&outp[(tokb + qr0A + lq) * 1024 + h * 64 + dt * 16 + g * 4] = ovA;
        *(bf16x4*)&outp[(tokb + qr0B + lq) * 1024 + h * 64 + dt * 16 + g * 4] = ovB;
    }
#undef STAGE
#undef WRITE_V
#undef QK_ONE
#undef MASK_ONE
#undef EXP_ONE
#undef PV_ONE
}

// ---------------- launch ----------------
extern "C" void kernel_launch(void* const* d_in, const int* in_sizes, int n_in,
                              void* d_out, int out_size, void* d_ws, size_t ws_size,
                              hipStream_t stream) {
    const float* x       = (const float*)d_in[0];
    const float* cosv    = (const float*)d_in[1];
    const float* sinv    = (const float*)d_in[2];
    const float* wq      = (const float*)d_in[4];
    const float* wk      = (const float*)d_in[5];
    const float* wv      = (const float*)d_in[6];
    const float* wo      = (const float*)d_in[7];
    const float* wgate   = (const float*)d_in[8];
    const float* wup     = (const float*)d_in[9];
    const float* wdown   = (const float*)d_in[10];
    const float* norm1   = (const float*)d_in[11];
    const float* norm2   = (const float*)d_in[12];
    const float* ls_attn = (const float*)d_in[13];
    const float* ls_mlp  = (const float*)d_in[14];

    char* ws = (char*)d_ws;
    __bf16* wqkvT = (__bf16*)(ws + OFF_WQKVT);
    __bf16* woT   = (__bf16*)(ws + OFF_WOT);
    __bf16* wguT  = (__bf16*)(ws + OFF_WGUT);
    __bf16* wdT   = (__bf16*)(ws + OFF_WDT);
    __bf16* hb    = (__bf16*)(ws + OFF_HB);
    __bf16* qkvb  = (__bf16*)(ws + OFF_QKV);
    __bf16* attnb = (__bf16*)(ws + OFF_ATTN);
    float*  h2    = (float*)(ws + OFF_H2);
    __bf16* gb    = (__bf16*)(ws + OFF_G);
    __bf16* mb    = (__bf16*)(ws + OFF_M);
    float*  outf  = (float*)d_out;

    prep_k<<<7680, 256, 0, stream>>>(
        wq, wk, wv, wo, wgate, wup, wdown, wqkvT, woT, wguT, wdT, x, norm1, hb);
    gemm_bt<1, 128, 128, 64><<<dim3(QKVN / 128, NTOK / 128), 256, 0, stream>>>(
        hb, wqkvT, NTOK, QKVN, 512, qkvb, nullptr, nullptr, nullptr, cosv, sinv);
    attn_k<<<dim3(NB * NHEAD, 16), 256, 0, stream>>>(qkvb, attnb);
    gemm_bt<2, 64, 64, 128><<<dim3(HIDD / 64, NTOK / 64), 256, 0, stream>>>(
        attnb, woT, NTOK, HIDD, 1024, nullptr, h2, x, ls_attn, nullptr, nullptr);
    rmsnorm_k<<<NTOK, 256, 0, stream>>>(h2, norm2, gb);
    gemm_bt<3, 128, 128, 64><<<dim3(GUN / 128, NTOK / 128), 256, 0, stream>>>(
        gb, wguT, NTOK, GUN, 512, mb, nullptr, nullptr, nullptr, nullptr, nullptr);
    gemm_bt<2, 64, 64, 128><<<dim3(HIDD / 64, NTOK / 64), 256, 0, stream>>>(
        mb, wdT, NTOK, HIDD, 1024, nullptr, outf, h2, ls_mlp, nullptr, nullptr);
}

// Round 14
// 115.004 us; speedup vs baseline: 1.3600x; 1.0312x over previous
//
#include <hip/hip_runtime.h>
#include <hip/hip_bf16.h>

typedef __bf16 bf16x8 __attribute__((ext_vector_type(8)));
typedef __bf16 bf16x4 __attribute__((ext_vector_type(4)));
typedef float f32x4 __attribute__((ext_vector_type(4)));

#define SEQ   2048
#define NB    2
#define NTOK  4096
#define HIDD  512
#define NHEAD 16
#define DHEAD 64
#define QKVN  3072
#define GUN   2048

// workspace layout (bytes)
#define OFF_WQKVT  0u
#define OFF_WOT    3145728u
#define OFF_WGUT   4194304u
#define OFF_WDT    6291456u
#define OFF_HB     7340032u
#define OFF_QKV    11534336u
#define OFF_ATTN   36700160u
#define OFF_H2     45088768u
#define OFF_G      53477376u
#define OFF_M      (OFF_QKV + 16777216u)

#define QSCALE 0.1803368801111731f           // 0.125 * log2(e): exp2-domain scores

#if __has_builtin(__builtin_amdgcn_exp2f)
#define EXP2(x) __builtin_amdgcn_exp2f(x)
#else
#define EXP2(x) exp2f(x)
#endif

typedef unsigned int __attribute__((address_space(1))) as1_uint;
typedef unsigned int __attribute__((address_space(3))) as3_uint;
__device__ __forceinline__ void gload16(const void* g, void* l) {
    __builtin_amdgcn_global_load_lds((const as1_uint*)g, (as3_uint*)l, 16, 0, 0);
}

// ---------------- fused prep: 7 weight transposes + rmsnorm1, one launch ----
__global__ __launch_bounds__(256) void prep_k(
    const float* __restrict__ wq, const float* __restrict__ wk,
    const float* __restrict__ wv, const float* __restrict__ wo,
    const float* __restrict__ wg, const float* __restrict__ wu,
    const float* __restrict__ wd,
    __bf16* __restrict__ qkvT, __bf16* __restrict__ woT,
    __bf16* __restrict__ wguT, __bf16* __restrict__ wdT,
    const float* __restrict__ x, const float* __restrict__ norm1,
    __bf16* __restrict__ hb) {
    __shared__ float t[32][33];
    int bid = blockIdx.x;
    if (bid < 3584) {
        int which = bid >> 9, bx = bid & 511;
        const float* in; __bf16* out; int K, N, mode = 0, phase = 0;
        switch (which) {
            case 0: in = wq; out = qkvT;              K = 512;  N = 1024; break;
            case 1: in = wk; out = qkvT + 1024 * 512; K = 512;  N = 1024; break;
            case 2: in = wv; out = qkvT + 2048 * 512; K = 512;  N = 1024; break;
            case 3: in = wo; out = woT;               K = 1024; N = 512;  break;
            case 4: in = wg; out = wguT;              K = 512;  N = 1024; mode = 1; phase = 0; break;
            case 5: in = wu; out = wguT;              K = 512;  N = 1024; mode = 1; phase = 1; break;
            default: in = wd; out = wdT;              K = 1024; N = 512;  break;
        }
        int ntn = N >> 5;
        int n0 = (bx & (ntn - 1)) * 32;
        int k0 = (bx / ntn) * 32;
        int tx = threadIdx.x & 31, ty = threadIdx.x >> 5;
#pragma unroll
        for (int j = 0; j < 4; ++j)
            t[ty * 4 + j][tx] = in[(size_t)(k0 + ty * 4 + j) * N + n0 + tx];
        __syncthreads();
#pragma unroll
        for (int j = 0; j < 4; ++j) {
            int n = n0 + ty * 4 + j;
            int row = mode ? (((n >> 4) << 5) + phase * 16 + (n & 15)) : n;
            out[(size_t)row * K + k0 + tx] = (__bf16)t[tx][ty * 4 + j];
        }
    } else {
        int row = bid - 3584;
        int tt = threadIdx.x;
        const float* xr = x + (size_t)row * HIDD;
        float2 v = *(const float2*)&xr[tt * 2];
        float ss = v.x * v.x + v.y * v.y;
#pragma unroll
        for (int off = 32; off >= 1; off >>= 1) ss += __shfl_xor(ss, off);
        if ((tt & 63) == 0) t[0][tt >> 6] = ss;
        __syncthreads();
        float tot = t[0][0] + t[0][1] + t[0][2] + t[0][3];
        float r = rsqrtf(tot * (1.0f / HIDD) + 1e-8f);
        hb[(size_t)row * HIDD + tt * 2]     = (__bf16)(v.x * r * norm1[tt * 2]);
        hb[(size_t)row * HIDD + tt * 2 + 1] = (__bf16)(v.y * r * norm1[tt * 2 + 1]);
    }
}

// ---------------- RMSNorm (standalone, for norm2) ----------------
__global__ __launch_bounds__(256) void rmsnorm_k(const float* __restrict__ x,
                                                 const float* __restrict__ w,
                                                 __bf16* __restrict__ out) {
    int row = blockIdx.x;
    int t = threadIdx.x;
    const float* xr = x + (size_t)row * HIDD;
    float2 v = *(const float2*)&xr[t * 2];
    float ss = v.x * v.x + v.y * v.y;
#pragma unroll
    for (int off = 32; off >= 1; off >>= 1) ss += __shfl_xor(ss, off);
    __shared__ float red[4];
    if ((t & 63) == 0) red[t >> 6] = ss;
    __syncthreads();
    float tot = red[0] + red[1] + red[2] + red[3];
    float r = rsqrtf(tot * (1.0f / HIDD) + 1e-8f);
    out[(size_t)row * HIDD + t * 2]     = (__bf16)(v.x * r * w[t * 2]);
    out[(size_t)row * HIDD + t * 2 + 1] = (__bf16)(v.y * r * w[t * 2 + 1]);
}

// ---------------- GEMM: C[M][N] = A[M][K] * Bt[N][K]^T ----------------
// BK template param; XOR source-swizzled LDS; XCD-aware block swizzle (T1).
template <int EPI, int TM, int TN, int BK>
__global__ __launch_bounds__(256) void gemm_bt(const __bf16* __restrict__ A,
                                               const __bf16* __restrict__ Bt,
                                               int M, int N, int K,
                                               __bf16* __restrict__ Cb,
                                               float* __restrict__ Cf,
                                               const float* __restrict__ resid,
                                               const float* __restrict__ scale,
                                               const float* __restrict__ cosv,
                                               const float* __restrict__ sinv) {
    __shared__ alignas(16) __bf16 As[TM][BK];
    __shared__ alignas(16) __bf16 Bs[TN][BK];
    constexpr int MI = TM / 32, NI = TN / 32;
    constexpr int CPB = BK / 8;
    int nwg = gridDim.x * gridDim.y;
    int bid = blockIdx.y * gridDim.x + blockIdx.x;
    int swz = (bid & 7) * (nwg >> 3) + (bid >> 3);
    int bx = swz % gridDim.x, by = swz / gridDim.x;
    int m0 = by * TM, n0 = bx * TN;
    int tid = threadIdx.x;
    int lane = tid & 63, w = tid >> 6;
    int wm = (w >> 1) * (TM / 2), wn = (w & 1) * (TN / 2);
    int lr = lane & 15, lkg = lane >> 4;
    f32x4 acc[MI][NI] = {};
    int nkt = K / BK;
    for (int kt = 0; kt < nkt; ++kt) {
        __syncthreads();
#pragma unroll
        for (int i = 0; i < (TM * BK) / 2048; ++i) {
            int c = i * 256 + tid;
            int row = c / CPB, ch = c % CPB;
            gload16(&A[(size_t)(m0 + row) * K + kt * BK + ((ch ^ (row & 7)) << 3)],
                    (__bf16*)As + c * 8);
        }
#pragma unroll
        for (int i = 0; i < (TN * BK) / 2048; ++i) {
            int c = i * 256 + tid;
            int row = c / CPB, ch = c % CPB;
            gload16(&Bt[(size_t)(n0 + row) * K + kt * BK + ((ch ^ (row & 7)) << 3)],
                    (__bf16*)Bs + c * 8);
        }
        __syncthreads();
#pragma unroll
        for (int kk = 0; kk < BK / 32; ++kk) {
            bf16x8 af[MI], bfv[NI];
#pragma unroll
            for (int mi = 0; mi < MI; ++mi) {
                int row = wm + mi * 16 + lr;
                af[mi] = *(const bf16x8*)&As[row][(((kk * 4 + lkg) ^ (row & 7)) << 3)];
            }
#pragma unroll
            for (int ni = 0; ni < NI; ++ni) {
                int row = wn + ni * 16 + lr;
                bfv[ni] = *(const bf16x8*)&Bs[row][(((kk * 4 + lkg) ^ (row & 7)) << 3)];
            }
#pragma unroll
            for (int mi = 0; mi < MI; ++mi)
#pragma unroll
                for (int ni = 0; ni < NI; ++ni)
                    acc[mi][ni] = __builtin_amdgcn_mfma_f32_16x16x32_bf16(
                        af[mi], bfv[ni], acc[mi][ni], 0, 0, 0);
        }
    }
    if (EPI == 1) {
        bool do_rope = (n0 + wn) < 2048;
        float qf = (n0 + wn) < 1024 ? QSCALE : 1.0f;
#pragma unroll
        for (int mi = 0; mi < MI; ++mi)
#pragma unroll
            for (int r = 0; r < 4; ++r) {
                int row = m0 + wm + mi * 16 + (lane >> 4) * 4 + r;
                int s = row & (SEQ - 1);
#pragma unroll
                for (int ni = 0; ni < 2; ++ni) {
                    float v1 = acc[mi][ni][r], v2 = acc[mi][ni + 2][r];
                    size_t i1 = (size_t)row * N + n0 + wn + ni * 16 + lr;
                    size_t i2 = i1 + 32;
                    if (do_rope) {
                        int d = ni * 16 + lr;
                        float c = cosv[s * 32 + d], sn = sinv[s * 32 + d];
                        Cb[i1] = (__bf16)((v1 * c - v2 * sn) * qf);
                        Cb[i2] = (__bf16)((v2 * c + v1 * sn) * qf);
                    } else {
                        Cb[i1] = (__bf16)v1;
                        Cb[i2] = (__bf16)v2;
                    }
                }
            }
    } else if (EPI == 3) {
#pragma unroll
        for (int mi = 0; mi < MI; ++mi)
#pragma unroll
            for (int r = 0; r < 4; ++r) {
                int row = m0 + wm + mi * 16 + (lane >> 4) * 4 + r;
#pragma unroll
                for (int ni = 0; ni < 4; ni += 2) {
                    float g = acc[mi][ni][r], u = acc[mi][ni + 1][r];
                    float mv = (g / (1.0f + __expf(-g))) * u;
                    int j = (((n0 + wn + ni * 16) >> 5) << 4) + lr;
                    Cb[(size_t)row * 1024 + j] = (__bf16)mv;
                }
            }
    } else {
#pragma unroll
        for (int mi = 0; mi < MI; ++mi)
#pragma unroll
            for (int ni = 0; ni < NI; ++ni)
#pragma unroll
                for (int r = 0; r < 4; ++r) {
                    int row = m0 + wm + mi * 16 + (lane >> 4) * 4 + r;
                    int col = n0 + wn + ni * 16 + lr;
                    size_t idx = (size_t)row * N + col;
                    float vv = acc[mi][ni][r];
                    if (EPI == 0) Cb[idx] = (__bf16)vv;
                    else          Cf[idx] = resid[idx] + vv * scale[col];
                }
    }
}

// ---------------- causal flash attention: dual wave-group, split-K-in-block ----------------
// 512 threads = 8 waves = 2 groups of 4. No-max softmax partials are LINEAR
// (merge = add) -> split tile B's K-range across groups with no rescale:
//   grp0: tile B kb 0..16 (17 steps; TB=32-y >= 17 always)
//   grp1: tile A kb 0..y (reads grp0's stream - same K/V, zero dup staging)
//         then tile B kb 17..TB-1 from its own stream.  (y+1)+(15-y)=16 steps.
// Every block: 17 lockstep iterations -> perfectly uniform grid. Staging = TB
// tiles = minimal. Grid 512 x 512thr -> 2 blocks/CU x 8 waves = 4 waves/SIMD
// (2x r10) with zero extra work/traffic (r7/r12 lessons). LDS 64KB: 2 streams
// x dbuf x (8K K + 8K V). B-partials merged via LDS add. VGPR ~100 <= 128 cap.
__global__ __launch_bounds__(512, 4) void attn_k(const __bf16* __restrict__ qkv,
                                                 __bf16* __restrict__ outp) {
    __shared__ alignas(16) __bf16 KS[2][2][4096];   // [grp][buf][64key x 64d]
    __shared__ alignas(16) __bf16 VS[2][2][4096];   // [grp][buf][64dv x 64key]
    int bh = blockIdx.x;
    int b = bh >> 4, h = bh & 15;
    int y = blockIdx.y;                  // 0..15
    int qbA = y, qbB = 31 - y;
    int TA = y + 1;
    int tid = threadIdx.x;
    int grp = tid >> 8;                  // wave-group 0/1
    int tg  = tid & 255;
    int lane = tid & 63, wg = tg >> 6;   // wave-in-group 0..3
    int lq = lane & 15, g = lane >> 4;
    size_t tokb = (size_t)b * SEQ;
    int qr0A = qbA * 64 + wg * 16, qr0B = qbB * 64 + wg * 16;

    // V staging constants (r6-verified pi-key layout)
    int vslot = ((lane >> 5) << 2) + ((lane >> 2) & 3);
    int vke   = (((lane >> 4) & 1) << 2) + (lane & 3);

    bf16x8 ones8;
#pragma unroll
    for (int e = 0; e < 8; ++e) ones8[e] = (__bf16)1.0f;

    bf16x8 aqB[2], aqA[2];
#pragma unroll
    for (int ks = 0; ks < 2; ++ks)
        aqB[ks] = *(const bf16x8*)&qkv[(tokb + qr0B + lq) * QKVN + h * 64 + ks * 32 + g * 8];
    if (grp == 1) {
#pragma unroll
        for (int ks = 0; ks < 2; ++ks)
            aqA[ks] = *(const bf16x8*)&qkv[(tokb + qr0A + lq) * QKVN + h * 64 + ks * 32 + g * 8];
    }

    f32x4 oa[4] = {};
    f32x4 ol = {};
    uint4 vv0, vv1;

#define STAGE_K(kbn, kdst)                                                                         \
    {                                                                                              \
        _Pragma("unroll")                                                                          \
        for (int i = 0; i < 2; ++i) {                                                              \
            int c = i * 256 + tg;                                                                  \
            int kr = c >> 3, sw = c & 7;                                                           \
            gload16(&qkv[(tokb + (kbn) * 64 + kr) * QKVN + 1024 + h * 64 + ((sw ^ (kr & 7)) << 3)], \
                    (kdst) + c * 8);                                                               \
        }                                                                                          \
    }

#define LOAD_V(kbn)                                                                                \
    {                                                                                              \
        const __bf16* vp = &qkv[(tokb + (kbn) * 64 + lane) * QKVN + 2048 + h * 64];                \
        vv0 = *(const uint4*)(vp + (wg * 2) * 8);                                                  \
        vv1 = *(const uint4*)(vp + (wg * 2 + 1) * 8);                                              \
    }

#define WRITE_Vg(vdst)                                                                \
    {                                                                                 \
        const __bf16* ve0 = (const __bf16*)&vv0;                                      \
        const __bf16* ve1 = (const __bf16*)&vv1;                                      \
        _Pragma("unroll")                                                             \
        for (int j = 0; j < 8; ++j) {                                                 \
            int dv0 = (wg * 2) * 8 + j, dv1 = (wg * 2 + 1) * 8 + j;                   \
            (vdst)[dv0 * 64 + ((vslot ^ j) << 3) + vke] = ve0[j];                     \
            (vdst)[dv1 * 64 + ((vslot ^ j) << 3) + vke] = ve1[j];                     \
        }                                                                             \
    }

#define QK_S(sc, aq, ksrc)                                                                         \
    {                                                                                              \
        __builtin_amdgcn_s_setprio(1);                                                             \
        _Pragma("unroll")                                                                          \
        for (int jt = 0; jt < 4; ++jt)                                                             \
            _Pragma("unroll")                                                                      \
            for (int ks = 0; ks < 2; ++ks) {                                                       \
                bf16x8 bk = *(const bf16x8*)&(ksrc)[(jt * 16 + lq) * 64 + (((ks * 4 + g) ^ (lq & 7)) << 3)]; \
                sc[jt] = __builtin_amdgcn_mfma_f32_16x16x32_bf16(bk, aq[ks], sc[jt], 0, 0, 0);     \
            }                                                                                      \
        __builtin_amdgcn_s_setprio(0);                                                             \
    }

#define MASK_S(sc, qr0_t, kb64)                                                                    \
    {                                                                                              \
        int qabs = (qr0_t) + lq;                                                                   \
        _Pragma("unroll")                                                                          \
        for (int jt = 0; jt < 4; ++jt)                                                             \
            _Pragma("unroll")                                                                      \
            for (int r = 0; r < 4; ++r) {                                                          \
                int key = (kb64) * 64 + jt * 16 + g * 4 + r;                                       \
                if (key > qabs) sc[jt][r] = -1e9f;                                                 \
            }                                                                                      \
    }

#define EXP_S(sc)                                                                                  \
    _Pragma("unroll")                                                                              \
    for (int jt = 0; jt < 4; ++jt)                                                                 \
        _Pragma("unroll")                                                                          \
        for (int r = 0; r < 4; ++r) sc[jt][r] = EXP2(sc[jt][r]);

#define PV_S(sc, vsrc)                                                                             \
    {                                                                                              \
        __builtin_amdgcn_s_setprio(1);                                                             \
        _Pragma("unroll")                                                                          \
        for (int ks2 = 0; ks2 < 2; ++ks2) {                                                        \
            bf16x8 pfv;                                                                            \
            _Pragma("unroll")                                                                      \
            for (int e = 0; e < 4; ++e) {                                                          \
                pfv[e]     = (__bf16)sc[2 * ks2][e];                                               \
                pfv[e + 4] = (__bf16)sc[2 * ks2 + 1][e];                                           \
            }                                                                                      \
            ol = __builtin_amdgcn_mfma_f32_16x16x32_bf16(ones8, pfv, ol, 0, 0, 0);                 \
            _Pragma("unroll")                                                                      \
            for (int dt = 0; dt < 4; ++dt) {                                                       \
                bf16x8 av = *(const bf16x8*)&(vsrc)[(dt * 16 + lq) * 64 + (((ks2 * 4 + g) ^ (lq & 7)) << 3)]; \
                oa[dt] = __builtin_amdgcn_mfma_f32_16x16x32_bf16(av, pfv, oa[dt], 0, 0, 0);        \
            }                                                                                      \
        }                                                                                          \
        __builtin_amdgcn_s_setprio(0);                                                             \
    }

    // ---- prologue: grp0 stages kb=0 into stream0 buf0 ----
    if (grp == 0) {
        STAGE_K(0, KS[0][0]);
        LOAD_V(0);
        WRITE_Vg(VS[0][0]);
    }
    __syncthreads();

    for (int it = 0; it < 17; ++it) {
        int buf0 = it & 1;
        if (grp == 0) {
            bool pf = (it + 1) <= 16;
            if (pf) {
                STAGE_K(it + 1, KS[0][buf0 ^ 1]);
                LOAD_V(it + 1);
            }
            f32x4 sc[4] = {};
            QK_S(sc, aqB, KS[0][buf0]);
            if (it == qbB) MASK_S(sc, qr0B, it);
            EXP_S(sc);
            PV_S(sc, VS[0][buf0]);
            if (pf) WRITE_Vg(VS[0][buf0 ^ 1]);
        } else {
            int nit = it + 1;
            bool st = (nit >= TA) && (nit <= 15);
            int jn = nit - TA;
            if (st) {
                STAGE_K(17 + jn, KS[1][jn & 1]);
                LOAD_V(17 + jn);
            }
            if (it < TA) {
                // tile A, K/V from grp0's stream (same kb=it tile)
                f32x4 sc[4] = {};
                QK_S(sc, aqA, KS[0][buf0]);
                if (it == qbA) MASK_S(sc, qr0A, it);
                EXP_S(sc);
                PV_S(sc, VS[0][buf0]);
                if (it == TA - 1) {
                    // tile A complete: write output, reset accumulators for B-part
                    float inv = 1.0f / ol[0];
#pragma unroll
                    for (int dt = 0; dt < 4; ++dt) {
                        bf16x4 ov;
#pragma unroll
                        for (int r = 0; r < 4; ++r) ov[r] = (__bf16)(oa[dt][r] * inv);
                        *(bf16x4*)&outp[(tokb + qr0A + lq) * 1024 + h * 64 + dt * 16 + g * 4] = ov;
                        oa[dt] = (f32x4){0.f, 0.f, 0.f, 0.f};
                    }
                    ol = (f32x4){0.f, 0.f, 0.f, 0.f};
                }
            } else if (it <= 15) {
                int j = it - TA;
                int kb = 17 + j;
                f32x4 sc[4] = {};
                QK_S(sc, aqB, KS[1][j & 1]);
                if (kb == qbB) MASK_S(sc, qr0B, kb);
                EXP_S(sc);
                PV_S(sc, VS[1][j & 1]);
            }
            if (st) WRITE_Vg(VS[1][jn & 1]);
        }
        __syncthreads();
    }

    // ---- merge tile B partials (linear: just add) ----
    float* mrg_oa = (float*)KS[1];       // 16KB: 256 thr x 16 f32 (stream1 dead)
    float* mrg_ol = (float*)VS[1];       // 1KB
    if (grp == 1) {
#pragma unroll
        for (int dt = 0; dt < 4; ++dt)
#pragma unroll
            for (int r = 0; r < 4; ++r) mrg_oa[tg * 16 + dt * 4 + r] = oa[dt][r];
        mrg_ol[tg] = ol[0];
    }
    __syncthreads();
    if (grp == 0) {
        float l = ol[0] + mrg_ol[tg];
        float inv = 1.0f / l;
#pragma unroll
        for (int dt = 0; dt < 4; ++dt) {
            bf16x4 ov;
#pragma unroll
            for (int r = 0; r < 4; ++r)
                ov[r] = (__bf16)((oa[dt][r] + mrg_oa[tg * 16 + dt * 4 + r]) * inv);
            *(bf16x4*)&outp[(tokb + qr0B + lq) * 1024 + h * 64 + dt * 16 + g * 4] = ov;
        }
    }
#undef STAGE_K
#undef LOAD_V
#undef WRITE_Vg
#undef QK_S
#undef MASK_S
#undef EXP_S
#undef PV_S
}

// ---------------- launch ----------------
extern "C" void kernel_launch(void* const* d_in, const int* in_sizes, int n_in,
                              void* d_out, int out_size, void* d_ws, size_t ws_size,
                              hipStream_t stream) {
    const float* x       = (const float*)d_in[0];
    const float* cosv    = (const float*)d_in[1];
    const float* sinv    = (const float*)d_in[2];
    const float* wq      = (const float*)d_in[4];
    const float* wk      = (const float*)d_in[5];
    const float* wv      = (const float*)d_in[6];
    const float* wo      = (const float*)d_in[7];
    const float* wgate   = (const float*)d_in[8];
    const float* wup     = (const float*)d_in[9];
    const float* wdown   = (const float*)d_in[10];
    const float* norm1   = (const float*)d_in[11];
    const float* norm2   = (const float*)d_in[12];
    const float* ls_attn = (const float*)d_in[13];
    const float* ls_mlp  = (const float*)d_in[14];

    char* ws = (char*)d_ws;
    __bf16* wqkvT = (__bf16*)(ws + OFF_WQKVT);
    __bf16* woT   = (__bf16*)(ws + OFF_WOT);
    __bf16* wguT  = (__bf16*)(ws + OFF_WGUT);
    __bf16* wdT   = (__bf16*)(ws + OFF_WDT);
    __bf16* hb    = (__bf16*)(ws + OFF_HB);
    __bf16* qkvb  = (__bf16*)(ws + OFF_QKV);
    __bf16* attnb = (__bf16*)(ws + OFF_ATTN);
    float*  h2    = (float*)(ws + OFF_H2);
    __bf16* gb    = (__bf16*)(ws + OFF_G);
    __bf16* mb    = (__bf16*)(ws + OFF_M);
    float*  outf  = (float*)d_out;

    prep_k<<<7680, 256, 0, stream>>>(
        wq, wk, wv, wo, wgate, wup, wdown, wqkvT, woT, wguT, wdT, x, norm1, hb);
    gemm_bt<1, 128, 128, 64><<<dim3(QKVN / 128, NTOK / 128), 256, 0, stream>>>(
        hb, wqkvT, NTOK, QKVN, 512, qkvb, nullptr, nullptr, nullptr, cosv, sinv);
    attn_k<<<dim3(NB * NHEAD, 16), 512, 0, stream>>>(qkvb, attnb);
    gemm_bt<2, 64, 64, 128><<<dim3(HIDD / 64, NTOK / 64), 256, 0, stream>>>(
        attnb, woT, NTOK, HIDD, 1024, nullptr, h2, x, ls_attn, nullptr, nullptr);
    rmsnorm_k<<<NTOK, 256, 0, stream>>>(h2, norm2, gb);
    gemm_bt<3, 128, 128, 64><<<dim3(GUN / 128, NTOK / 128), 256, 0, stream>>>(
        gb, wguT, NTOK, GUN, 512, mb, nullptr, nullptr, nullptr, nullptr, nullptr);
    gemm_bt<2, 64, 64, 128><<<dim3(HIDD / 64, NTOK / 64), 256, 0, stream>>>(
        mb, wdT, NTOK, HIDD, 1024, nullptr, outf, h2, ls_mlp, nullptr, nullptr);
}

// Round 15
// 112.944 us; speedup vs baseline: 1.3848x; 1.0182x over previous
//
#include <hip/hip_runtime.h>
#include <hip/hip_bf16.h>

typedef __bf16 bf16x8 __attribute__((ext_vector_type(8)));
typedef __bf16 bf16x4 __attribute__((ext_vector_type(4)));
typedef float f32x4 __attribute__((ext_vector_type(4)));

#define SEQ   2048
#define NB    2
#define NTOK  4096
#define HIDD  512
#define NHEAD 16
#define DHEAD 64
#define QKVN  3072
#define GUN   2048

// workspace layout (bytes)
#define OFF_WQKVT  0u
#define OFF_WOT    3145728u
#define OFF_WGUT   4194304u
#define OFF_WDT    6291456u
#define OFF_HB     7340032u
#define OFF_QKV    11534336u
#define OFF_ATTN   36700160u
#define OFF_H2     45088768u
#define OFF_G      53477376u
#define OFF_M      (OFF_QKV + 16777216u)

#define QSCALE 0.1803368801111731f           // 0.125 * log2(e): exp2-domain scores

#if __has_builtin(__builtin_amdgcn_exp2f)
#define EXP2(x) __builtin_amdgcn_exp2f(x)
#else
#define EXP2(x) exp2f(x)
#endif

typedef unsigned int __attribute__((address_space(1))) as1_uint;
typedef unsigned int __attribute__((address_space(3))) as3_uint;
__device__ __forceinline__ void gload16(const void* g, void* l) {
    __builtin_amdgcn_global_load_lds((const as1_uint*)g, (as3_uint*)l, 16, 0, 0);
}

// ---------------- fused prep: 7 weight transposes + rmsnorm1, one launch ----
__global__ __launch_bounds__(256) void prep_k(
    const float* __restrict__ wq, const float* __restrict__ wk,
    const float* __restrict__ wv, const float* __restrict__ wo,
    const float* __restrict__ wg, const float* __restrict__ wu,
    const float* __restrict__ wd,
    __bf16* __restrict__ qkvT, __bf16* __restrict__ woT,
    __bf16* __restrict__ wguT, __bf16* __restrict__ wdT,
    const float* __restrict__ x, const float* __restrict__ norm1,
    __bf16* __restrict__ hb) {
    __shared__ float t[32][33];
    int bid = blockIdx.x;
    if (bid < 3584) {
        int which = bid >> 9, bx = bid & 511;
        const float* in; __bf16* out; int K, N, mode = 0, phase = 0;
        switch (which) {
            case 0: in = wq; out = qkvT;              K = 512;  N = 1024; break;
            case 1: in = wk; out = qkvT + 1024 * 512; K = 512;  N = 1024; break;
            case 2: in = wv; out = qkvT + 2048 * 512; K = 512;  N = 1024; break;
            case 3: in = wo; out = woT;               K = 1024; N = 512;  break;
            case 4: in = wg; out = wguT;              K = 512;  N = 1024; mode = 1; phase = 0; break;
            case 5: in = wu; out = wguT;              K = 512;  N = 1024; mode = 1; phase = 1; break;
            default: in = wd; out = wdT;              K = 1024; N = 512;  break;
        }
        int ntn = N >> 5;
        int n0 = (bx & (ntn - 1)) * 32;
        int k0 = (bx / ntn) * 32;
        int tx = threadIdx.x & 31, ty = threadIdx.x >> 5;
#pragma unroll
        for (int j = 0; j < 4; ++j)
            t[ty * 4 + j][tx] = in[(size_t)(k0 + ty * 4 + j) * N + n0 + tx];
        __syncthreads();
#pragma unroll
        for (int j = 0; j < 4; ++j) {
            int n = n0 + ty * 4 + j;
            int row = mode ? (((n >> 4) << 5) + phase * 16 + (n & 15)) : n;
            out[(size_t)row * K + k0 + tx] = (__bf16)t[tx][ty * 4 + j];
        }
    } else {
        int row = bid - 3584;
        int tt = threadIdx.x;
        const float* xr = x + (size_t)row * HIDD;
        float2 v = *(const float2*)&xr[tt * 2];
        float ss = v.x * v.x + v.y * v.y;
#pragma unroll
        for (int off = 32; off >= 1; off >>= 1) ss += __shfl_xor(ss, off);
        if ((tt & 63) == 0) t[0][tt >> 6] = ss;
        __syncthreads();
        float tot = t[0][0] + t[0][1] + t[0][2] + t[0][3];
        float r = rsqrtf(tot * (1.0f / HIDD) + 1e-8f);
        hb[(size_t)row * HIDD + tt * 2]     = (__bf16)(v.x * r * norm1[tt * 2]);
        hb[(size_t)row * HIDD + tt * 2 + 1] = (__bf16)(v.y * r * norm1[tt * 2 + 1]);
    }
}

// ---------------- RMSNorm (standalone, for norm2) ----------------
__global__ __launch_bounds__(256) void rmsnorm_k(const float* __restrict__ x,
                                                 const float* __restrict__ w,
                                                 __bf16* __restrict__ out) {
    int row = blockIdx.x;
    int t = threadIdx.x;
    const float* xr = x + (size_t)row * HIDD;
    float2 v = *(const float2*)&xr[t * 2];
    float ss = v.x * v.x + v.y * v.y;
#pragma unroll
    for (int off = 32; off >= 1; off >>= 1) ss += __shfl_xor(ss, off);
    __shared__ float red[4];
    if ((t & 63) == 0) red[t >> 6] = ss;
    __syncthreads();
    float tot = red[0] + red[1] + red[2] + red[3];
    float r = rsqrtf(tot * (1.0f / HIDD) + 1e-8f);
    out[(size_t)row * HIDD + t * 2]     = (__bf16)(v.x * r * w[t * 2]);
    out[(size_t)row * HIDD + t * 2 + 1] = (__bf16)(v.y * r * w[t * 2 + 1]);
}

// ---------------- GEMM: C[M][N] = A[M][K] * Bt[N][K]^T ----------------
// BK template param; XOR source-swizzled LDS; XCD-aware block swizzle (T1).
template <int EPI, int TM, int TN, int BK>
__global__ __launch_bounds__(256) void gemm_bt(const __bf16* __restrict__ A,
                                               const __bf16* __restrict__ Bt,
                                               int M, int N, int K,
                                               __bf16* __restrict__ Cb,
                                               float* __restrict__ Cf,
                                               const float* __restrict__ resid,
                                               const float* __restrict__ scale,
                                               const float* __restrict__ cosv,
                                               const float* __restrict__ sinv) {
    __shared__ alignas(16) __bf16 As[TM][BK];
    __shared__ alignas(16) __bf16 Bs[TN][BK];
    constexpr int MI = TM / 32, NI = TN / 32;
    constexpr int CPB = BK / 8;
    int nwg = gridDim.x * gridDim.y;
    int bid = blockIdx.y * gridDim.x + blockIdx.x;
    int swz = (bid & 7) * (nwg >> 3) + (bid >> 3);
    int bx = swz % gridDim.x, by = swz / gridDim.x;
    int m0 = by * TM, n0 = bx * TN;
    int tid = threadIdx.x;
    int lane = tid & 63, w = tid >> 6;
    int wm = (w >> 1) * (TM / 2), wn = (w & 1) * (TN / 2);
    int lr = lane & 15, lkg = lane >> 4;
    f32x4 acc[MI][NI] = {};
    int nkt = K / BK;
    for (int kt = 0; kt < nkt; ++kt) {
        __syncthreads();
#pragma unroll
        for (int i = 0; i < (TM * BK) / 2048; ++i) {
            int c = i * 256 + tid;
            int row = c / CPB, ch = c % CPB;
            gload16(&A[(size_t)(m0 + row) * K + kt * BK + ((ch ^ (row & 7)) << 3)],
                    (__bf16*)As + c * 8);
        }
#pragma unroll
        for (int i = 0; i < (TN * BK) / 2048; ++i) {
            int c = i * 256 + tid;
            int row = c / CPB, ch = c % CPB;
            gload16(&Bt[(size_t)(n0 + row) * K + kt * BK + ((ch ^ (row & 7)) << 3)],
                    (__bf16*)Bs + c * 8);
        }
        __syncthreads();
#pragma unroll
        for (int kk = 0; kk < BK / 32; ++kk) {
            bf16x8 af[MI], bfv[NI];
#pragma unroll
            for (int mi = 0; mi < MI; ++mi) {
                int row = wm + mi * 16 + lr;
                af[mi] = *(const bf16x8*)&As[row][(((kk * 4 + lkg) ^ (row & 7)) << 3)];
            }
#pragma unroll
            for (int ni = 0; ni < NI; ++ni) {
                int row = wn + ni * 16 + lr;
                bfv[ni] = *(const bf16x8*)&Bs[row][(((kk * 4 + lkg) ^ (row & 7)) << 3)];
            }
#pragma unroll
            for (int mi = 0; mi < MI; ++mi)
#pragma unroll
                for (int ni = 0; ni < NI; ++ni)
                    acc[mi][ni] = __builtin_amdgcn_mfma_f32_16x16x32_bf16(
                        af[mi], bfv[ni], acc[mi][ni], 0, 0, 0);
        }
    }
    if (EPI == 1) {
        bool do_rope = (n0 + wn) < 2048;
        float qf = (n0 + wn) < 1024 ? QSCALE : 1.0f;
#pragma unroll
        for (int mi = 0; mi < MI; ++mi)
#pragma unroll
            for (int r = 0; r < 4; ++r) {
                int row = m0 + wm + mi * 16 + (lane >> 4) * 4 + r;
                int s = row & (SEQ - 1);
#pragma unroll
                for (int ni = 0; ni < 2; ++ni) {
                    float v1 = acc[mi][ni][r], v2 = acc[mi][ni + 2][r];
                    size_t i1 = (size_t)row * N + n0 + wn + ni * 16 + lr;
                    size_t i2 = i1 + 32;
                    if (do_rope) {
                        int d = ni * 16 + lr;
                        float c = cosv[s * 32 + d], sn = sinv[s * 32 + d];
                        Cb[i1] = (__bf16)((v1 * c - v2 * sn) * qf);
                        Cb[i2] = (__bf16)((v2 * c + v1 * sn) * qf);
                    } else {
                        Cb[i1] = (__bf16)v1;
                        Cb[i2] = (__bf16)v2;
                    }
                }
            }
    } else if (EPI == 3) {
#pragma unroll
        for (int mi = 0; mi < MI; ++mi)
#pragma unroll
            for (int r = 0; r < 4; ++r) {
                int row = m0 + wm + mi * 16 + (lane >> 4) * 4 + r;
#pragma unroll
                for (int ni = 0; ni < 4; ni += 2) {
                    float g = acc[mi][ni][r], u = acc[mi][ni + 1][r];
                    float mv = (g / (1.0f + __expf(-g))) * u;
                    int j = (((n0 + wn + ni * 16) >> 5) << 4) + lr;
                    Cb[(size_t)row * 1024 + j] = (__bf16)mv;
                }
            }
    } else {
#pragma unroll
        for (int mi = 0; mi < MI; ++mi)
#pragma unroll
            for (int ni = 0; ni < NI; ++ni)
#pragma unroll
                for (int r = 0; r < 4; ++r) {
                    int row = m0 + wm + mi * 16 + (lane >> 4) * 4 + r;
                    int col = n0 + wn + ni * 16 + lr;
                    size_t idx = (size_t)row * N + col;
                    float vv = acc[mi][ni][r];
                    if (EPI == 0) Cb[idx] = (__bf16)vv;
                    else          Cf[idx] = resid[idx] + vv * scale[col];
                }
    }
}

// ---------------- causal flash attention: dual wave-group, split-K-in-block ----------------
// r14 structure (occupancy 2x verified) RESTRUCTURED for register liveness:
// grp1's per-iteration branch -> two straight loops (A-loop reading grp0's
// stream, then B2-loop on its own stream); A-epilogue moved between loops;
// aqA dead before aqB loaded. r14's (512,4)=128 cap spill (WRITE 22.5MB vs
// 8.19 legit, VGPR=64) came from the branchy liveness - this removes it.
// Barrier counts: grp0 = 17 in-loop; grp1 = TA + (16-TA) + 1 explicit = 17;
// i-th barrier pairs with i-th -> same producer/consumer schedule as r14.
__global__ __launch_bounds__(512, 4) void attn_k(const __bf16* __restrict__ qkv,
                                                 __bf16* __restrict__ outp) {
    __shared__ alignas(16) __bf16 KS[2][2][4096];   // [grp][buf][64key x 64d]
    __shared__ alignas(16) __bf16 VS[2][2][4096];   // [grp][buf][64dv x 64key]
    int bh = blockIdx.x;
    int b = bh >> 4, h = bh & 15;
    int y = blockIdx.y;                  // 0..15
    int qbA = y, qbB = 31 - y;
    int TA = y + 1;
    int tid = threadIdx.x;
    int grp = tid >> 8;                  // wave-group 0/1
    int tg  = tid & 255;
    int lane = tid & 63, wg = tg >> 6;   // wave-in-group 0..3
    int lq = lane & 15, g = lane >> 4;
    size_t tokb = (size_t)b * SEQ;
    int qr0A = qbA * 64 + wg * 16, qr0B = qbB * 64 + wg * 16;

    // V staging constants (r6-verified pi-key layout)
    int vslot = ((lane >> 5) << 2) + ((lane >> 2) & 3);
    int vke   = (((lane >> 4) & 1) << 2) + (lane & 3);

    bf16x8 ones8;
#pragma unroll
    for (int e = 0; e < 8; ++e) ones8[e] = (__bf16)1.0f;

    f32x4 oa[4] = {};
    f32x4 ol = {};
    uint4 vv0, vv1;

#define STAGE_K(kbn, kdst)                                                                         \
    {                                                                                              \
        _Pragma("unroll")                                                                          \
        for (int i = 0; i < 2; ++i) {                                                              \
            int c = i * 256 + tg;                                                                  \
            int kr = c >> 3, sw = c & 7;                                                           \
            gload16(&qkv[(tokb + (kbn) * 64 + kr) * QKVN + 1024 + h * 64 + ((sw ^ (kr & 7)) << 3)], \
                    (kdst) + c * 8);                                                               \
        }                                                                                          \
    }

#define LOAD_V(kbn)                                                                                \
    {                                                                                              \
        const __bf16* vp = &qkv[(tokb + (kbn) * 64 + lane) * QKVN + 2048 + h * 64];                \
        vv0 = *(const uint4*)(vp + (wg * 2) * 8);                                                  \
        vv1 = *(const uint4*)(vp + (wg * 2 + 1) * 8);                                              \
    }

#define WRITE_Vg(vdst)                                                                \
    {                                                                                 \
        const __bf16* ve0 = (const __bf16*)&vv0;                                      \
        const __bf16* ve1 = (const __bf16*)&vv1;                                      \
        _Pragma("unroll")                                                             \
        for (int j = 0; j < 8; ++j) {                                                 \
            int dv0 = (wg * 2) * 8 + j, dv1 = (wg * 2 + 1) * 8 + j;                   \
            (vdst)[dv0 * 64 + ((vslot ^ j) << 3) + vke] = ve0[j];                     \
            (vdst)[dv1 * 64 + ((vslot ^ j) << 3) + vke] = ve1[j];                     \
        }                                                                             \
    }

#define QK_S(sc, aq, ksrc)                                                                         \
    {                                                                                              \
        __builtin_amdgcn_s_setprio(1);                                                             \
        _Pragma("unroll")                                                                          \
        for (int jt = 0; jt < 4; ++jt)                                                             \
            _Pragma("unroll")                                                                      \
            for (int ks = 0; ks < 2; ++ks) {                                                       \
                bf16x8 bk = *(const bf16x8*)&(ksrc)[(jt * 16 + lq) * 64 + (((ks * 4 + g) ^ (lq & 7)) << 3)]; \
                sc[jt] = __builtin_amdgcn_mfma_f32_16x16x32_bf16(bk, aq[ks], sc[jt], 0, 0, 0);     \
            }                                                                                      \
        __builtin_amdgcn_s_setprio(0);                                                             \
    }

#define MASK_S(sc, qr0_t, kb64)                                                                    \
    {                                                                                              \
        int qabs = (qr0_t) + lq;                                                                   \
        _Pragma("unroll")                                                                          \
        for (int jt = 0; jt < 4; ++jt)                                                             \
            _Pragma("unroll")                                                                      \
            for (int r = 0; r < 4; ++r) {                                                          \
                int key = (kb64) * 64 + jt * 16 + g * 4 + r;                                       \
                if (key > qabs) sc[jt][r] = -1e9f;                                                 \
            }                                                                                      \
    }

#define EXP_S(sc)                                                                                  \
    _Pragma("unroll")                                                                              \
    for (int jt = 0; jt < 4; ++jt)                                                                 \
        _Pragma("unroll")                                                                          \
        for (int r = 0; r < 4; ++r) sc[jt][r] = EXP2(sc[jt][r]);

#define PV_S(sc, vsrc)                                                                             \
    {                                                                                              \
        __builtin_amdgcn_s_setprio(1);                                                             \
        _Pragma("unroll")                                                                          \
        for (int ks2 = 0; ks2 < 2; ++ks2) {                                                        \
            bf16x8 pfv;                                                                            \
            _Pragma("unroll")                                                                      \
            for (int e = 0; e < 4; ++e) {                                                          \
                pfv[e]     = (__bf16)sc[2 * ks2][e];                                               \
                pfv[e + 4] = (__bf16)sc[2 * ks2 + 1][e];                                           \
            }                                                                                      \
            ol = __builtin_amdgcn_mfma_f32_16x16x32_bf16(ones8, pfv, ol, 0, 0, 0);                 \
            _Pragma("unroll")                                                                      \
            for (int dt = 0; dt < 4; ++dt) {                                                       \
                bf16x8 av = *(const bf16x8*)&(vsrc)[(dt * 16 + lq) * 64 + (((ks2 * 4 + g) ^ (lq & 7)) << 3)]; \
                oa[dt] = __builtin_amdgcn_mfma_f32_16x16x32_bf16(av, pfv, oa[dt], 0, 0, 0);        \
            }                                                                                      \
        }                                                                                          \
        __builtin_amdgcn_s_setprio(0);                                                             \
    }

    if (grp == 0) {
        // =================== group 0: tile B, kb 0..16 ===================
        bf16x8 aqB[2];
#pragma unroll
        for (int ks = 0; ks < 2; ++ks)
            aqB[ks] = *(const bf16x8*)&qkv[(tokb + qr0B + lq) * QKVN + h * 64 + ks * 32 + g * 8];
        STAGE_K(0, KS[0][0]);
        LOAD_V(0);
        WRITE_Vg(VS[0][0]);
        __syncthreads();                               // barrier 0 (pairs grp1's)
        for (int it = 0; it < 17; ++it) {              // barriers 1..17
            int buf = it & 1;
            bool pf = it < 16;
            if (pf) {
                STAGE_K(it + 1, KS[0][buf ^ 1]);
                LOAD_V(it + 1);
            }
            f32x4 sc[4] = {};
            QK_S(sc, aqB, KS[0][buf]);
            if (it == qbB) MASK_S(sc, qr0B, it);
            EXP_S(sc);
            PV_S(sc, VS[0][buf]);
            if (pf) WRITE_Vg(VS[0][buf ^ 1]);
            __syncthreads();
        }
    } else {
        // =================== group 1: tile A (shared stream), then B-tail ===================
        {
            bf16x8 aqA[2];
#pragma unroll
            for (int ks = 0; ks < 2; ++ks)
                aqA[ks] = *(const bf16x8*)&qkv[(tokb + qr0A + lq) * QKVN + h * 64 + ks * 32 + g * 8];
            __syncthreads();                           // barrier 0
            for (int it = 0; it < TA; ++it) {          // barriers 1..TA
                int buf = it & 1;
                if (it == TA - 1) {                    // prepare B-tail stream
                    STAGE_K(17, KS[1][0]);
                    LOAD_V(17);
                }
                f32x4 sc[4] = {};
                QK_S(sc, aqA, KS[0][buf]);
                if (it == qbA) MASK_S(sc, qr0A, it);
                EXP_S(sc);
                PV_S(sc, VS[0][buf]);
                if (it == TA - 1) WRITE_Vg(VS[1][0]);
                __syncthreads();
            }
        }
        // tile A epilogue (out of loop)
        {
            float inv = 1.0f / ol[0];
#pragma unroll
            for (int dt = 0; dt < 4; ++dt) {
                bf16x4 ov;
#pragma unroll
                for (int r = 0; r < 4; ++r) ov[r] = (__bf16)(oa[dt][r] * inv);
                *(bf16x4*)&outp[(tokb + qr0A + lq) * 1024 + h * 64 + dt * 16 + g * 4] = ov;
                oa[dt] = (f32x4){0.f, 0.f, 0.f, 0.f};
            }
            ol = (f32x4){0.f, 0.f, 0.f, 0.f};
        }
        // B-tail: kb 17..(qbB), count = 16 - TA
        {
            bf16x8 aqB[2];
#pragma unroll
            for (int ks = 0; ks < 2; ++ks)
                aqB[ks] = *(const bf16x8*)&qkv[(tokb + qr0B + lq) * QKVN + h * 64 + ks * 32 + g * 8];
            int cnt = 16 - TA;
            for (int j = 0; j < cnt; ++j) {            // barriers TA+1..16
                int buf = j & 1;
                if (j + 1 < cnt) {
                    STAGE_K(17 + j + 1, KS[1][buf ^ 1]);
                    LOAD_V(17 + j + 1);
                }
                f32x4 sc[4] = {};
                int kb = 17 + j;
                QK_S(sc, aqB, KS[1][buf]);
                if (kb == qbB) MASK_S(sc, qr0B, kb);
                EXP_S(sc);
                PV_S(sc, VS[1][buf]);
                if (j + 1 < cnt) WRITE_Vg(VS[1][buf ^ 1]);
                __syncthreads();
            }
        }
        __syncthreads();                               // barrier 17 (equalize)
    }

    // ---- merge tile B partials (linear: just add) ----
    float* mrg_oa = (float*)KS[1];       // stream-1 LDS dead now
    float* mrg_ol = (float*)VS[1];
    if (grp == 1) {
#pragma unroll
        for (int dt = 0; dt < 4; ++dt)
#pragma unroll
            for (int r = 0; r < 4; ++r) mrg_oa[tg * 16 + dt * 4 + r] = oa[dt][r];
        mrg_ol[tg] = ol[0];
    }
    __syncthreads();                                   // barrier 18 (both)
    if (grp == 0) {
        float l = ol[0] + mrg_ol[tg];
        float inv = 1.0f / l;
#pragma unroll
        for (int dt = 0; dt < 4; ++dt) {
            bf16x4 ov;
#pragma unroll
            for (int r = 0; r < 4; ++r)
                ov[r] = (__bf16)((oa[dt][r] + mrg_oa[tg * 16 + dt * 4 + r]) * inv);
            *(bf16x4*)&outp[(tokb + qr0B + lq) * 1024 + h * 64 + dt * 16 + g * 4] = ov;
        }
    }
#undef STAGE_K
#undef LOAD_V
#undef WRITE_Vg
#undef QK_S
#undef MASK_S
#undef EXP_S
#undef PV_S
}

// ---------------- launch ----------------
extern "C" void kernel_launch(void* const* d_in, const int* in_sizes, int n_in,
                              void* d_out, int out_size, void* d_ws, size_t ws_size,
                              hipStream_t stream) {
    const float* x       = (const float*)d_in[0];
    const float* cosv    = (const float*)d_in[1];
    const float* sinv    = (const float*)d_in[2];
    const float* wq      = (const float*)d_in[4];
    const float* wk      = (const float*)d_in[5];
    const float* wv      = (const float*)d_in[6];
    const float* wo      = (const float*)d_in[7];
    const float* wgate   = (const float*)d_in[8];
    const float* wup     = (const float*)d_in[9];
    const float* wdown   = (const float*)d_in[10];
    const float* norm1   = (const float*)d_in[11];
    const float* norm2   = (const float*)d_in[12];
    const float* ls_attn = (const float*)d_in[13];
    const float* ls_mlp  = (const float*)d_in[14];

    char* ws = (char*)d_ws;
    __bf16* wqkvT = (__bf16*)(ws + OFF_WQKVT);
    __bf16* woT   = (__bf16*)(ws + OFF_WOT);
    __bf16* wguT  = (__bf16*)(ws + OFF_WGUT);
    __bf16* wdT   = (__bf16*)(ws + OFF_WDT);
    __bf16* hb    = (__bf16*)(ws + OFF_HB);
    __bf16* qkvb  = (__bf16*)(ws + OFF_QKV);
    __bf16* attnb = (__bf16*)(ws + OFF_ATTN);
    float*  h2    = (float*)(ws + OFF_H2);
    __bf16* gb    = (__bf16*)(ws + OFF_G);
    __bf16* mb    = (__bf16*)(ws + OFF_M);
    float*  outf  = (float*)d_out;

    prep_k<<<7680, 256, 0, stream>>>(
        wq, wk, wv, wo, wgate, wup, wdown, wqkvT, woT, wguT, wdT, x, norm1, hb);
    gemm_bt<1, 128, 128, 64><<<dim3(QKVN / 128, NTOK / 128), 256, 0, stream>>>(
        hb, wqkvT, NTOK, QKVN, 512, qkvb, nullptr, nullptr, nullptr, cosv, sinv);
    attn_k<<<dim3(NB * NHEAD, 16), 512, 0, stream>>>(qkvb, attnb);
    gemm_bt<2, 64, 64, 128><<<dim3(HIDD / 64, NTOK / 64), 256, 0, stream>>>(
        attnb, woT, NTOK, HIDD, 1024, nullptr, h2, x, ls_attn, nullptr, nullptr);
    rmsnorm_k<<<NTOK, 256, 0, stream>>>(h2, norm2, gb);
    gemm_bt<3, 128, 128, 64><<<dim3(GUN / 128, NTOK / 128), 256, 0, stream>>>(
        gb, wguT, NTOK, GUN, 512, mb, nullptr, nullptr, nullptr, nullptr, nullptr);
    gemm_bt<2, 64, 64, 128><<<dim3(HIDD / 64, NTOK / 64), 256, 0, stream>>>(
        mb, wdT, NTOK, HIDD, 1024, nullptr, outf, h2, ls_mlp, nullptr, nullptr);
}

// Round 16
// 111.862 us; speedup vs baseline: 1.3982x; 1.0097x over previous
//
#include <hip/hip_runtime.h>
#include <hip/hip_bf16.h>

typedef __bf16 bf16x8 __attribute__((ext_vector_type(8)));
typedef __bf16 bf16x4 __attribute__((ext_vector_type(4)));
typedef float f32x4 __attribute__((ext_vector_type(4)));

#define SEQ   2048
#define NB    2
#define NTOK  4096
#define HIDD  512
#define NHEAD 16
#define DHEAD 64
#define QKVN  3072
#define GUN   2048

// workspace layout (bytes)
#define OFF_WQKVT  0u
#define OFF_WOT    3145728u
#define OFF_WGUT   4194304u
#define OFF_WDT    6291456u
#define OFF_HB     7340032u
#define OFF_QKV    11534336u
#define OFF_ATTN   36700160u
#define OFF_H2     45088768u      // f32 h2 later; kb [32][2048][64] bf16 during attn
#define OFF_G      53477376u
#define OFF_M      (OFF_QKV + 16777216u)   // mb later; vtb [32][64][2048] bf16 during attn

#define QSCALE 0.1803368801111731f           // 0.125 * log2(e): exp2-domain scores

#if __has_builtin(__builtin_amdgcn_exp2f)
#define EXP2(x) __builtin_amdgcn_exp2f(x)
#else
#define EXP2(x) exp2f(x)
#endif

typedef unsigned int __attribute__((address_space(1))) as1_uint;
typedef unsigned int __attribute__((address_space(3))) as3_uint;
__device__ __forceinline__ void gload16(const void* g, void* l) {
    __builtin_amdgcn_global_load_lds((const as1_uint*)g, (as3_uint*)l, 16, 0, 0);
}

// ---------------- fused prep: 7 weight transposes + rmsnorm1, one launch ----
__global__ __launch_bounds__(256) void prep_k(
    const float* __restrict__ wq, const float* __restrict__ wk,
    const float* __restrict__ wv, const float* __restrict__ wo,
    const float* __restrict__ wg, const float* __restrict__ wu,
    const float* __restrict__ wd,
    __bf16* __restrict__ qkvT, __bf16* __restrict__ woT,
    __bf16* __restrict__ wguT, __bf16* __restrict__ wdT,
    const float* __restrict__ x, const float* __restrict__ norm1,
    __bf16* __restrict__ hb) {
    __shared__ float t[32][33];
    int bid = blockIdx.x;
    if (bid < 3584) {
        int which = bid >> 9, bx = bid & 511;
        const float* in; __bf16* out; int K, N, mode = 0, phase = 0;
        switch (which) {
            case 0: in = wq; out = qkvT;              K = 512;  N = 1024; break;
            case 1: in = wk; out = qkvT + 1024 * 512; K = 512;  N = 1024; break;
            case 2: in = wv; out = qkvT + 2048 * 512; K = 512;  N = 1024; break;
            case 3: in = wo; out = woT;               K = 1024; N = 512;  break;
            case 4: in = wg; out = wguT;              K = 512;  N = 1024; mode = 1; phase = 0; break;
            case 5: in = wu; out = wguT;              K = 512;  N = 1024; mode = 1; phase = 1; break;
            default: in = wd; out = wdT;              K = 1024; N = 512;  break;
        }
        int ntn = N >> 5;
        int n0 = (bx & (ntn - 1)) * 32;
        int k0 = (bx / ntn) * 32;
        int tx = threadIdx.x & 31, ty = threadIdx.x >> 5;
#pragma unroll
        for (int j = 0; j < 4; ++j)
            t[ty * 4 + j][tx] = in[(size_t)(k0 + ty * 4 + j) * N + n0 + tx];
        __syncthreads();
#pragma unroll
        for (int j = 0; j < 4; ++j) {
            int n = n0 + ty * 4 + j;
            int row = mode ? (((n >> 4) << 5) + phase * 16 + (n & 15)) : n;
            out[(size_t)row * K + k0 + tx] = (__bf16)t[tx][ty * 4 + j];
        }
    } else {
        int row = bid - 3584;
        int tt = threadIdx.x;
        const float* xr = x + (size_t)row * HIDD;
        float2 v = *(const float2*)&xr[tt * 2];
        float ss = v.x * v.x + v.y * v.y;
#pragma unroll
        for (int off = 32; off >= 1; off >>= 1) ss += __shfl_xor(ss, off);
        if ((tt & 63) == 0) t[0][tt >> 6] = ss;
        __syncthreads();
        float tot = t[0][0] + t[0][1] + t[0][2] + t[0][3];
        float r = rsqrtf(tot * (1.0f / HIDD) + 1e-8f);
        hb[(size_t)row * HIDD + tt * 2]     = (__bf16)(v.x * r * norm1[tt * 2]);
        hb[(size_t)row * HIDD + tt * 2 + 1] = (__bf16)(v.y * r * norm1[tt * 2 + 1]);
    }
}

// ---------------- RMSNorm (standalone, for norm2) ----------------
__global__ __launch_bounds__(256) void rmsnorm_k(const float* __restrict__ x,
                                                 const float* __restrict__ w,
                                                 __bf16* __restrict__ out) {
    int row = blockIdx.x;
    int t = threadIdx.x;
    const float* xr = x + (size_t)row * HIDD;
    float2 v = *(const float2*)&xr[t * 2];
    float ss = v.x * v.x + v.y * v.y;
#pragma unroll
    for (int off = 32; off >= 1; off >>= 1) ss += __shfl_xor(ss, off);
    __shared__ float red[4];
    if ((t & 63) == 0) red[t >> 6] = ss;
    __syncthreads();
    float tot = red[0] + red[1] + red[2] + red[3];
    float r = rsqrtf(tot * (1.0f / HIDD) + 1e-8f);
    out[(size_t)row * HIDD + t * 2]     = (__bf16)(v.x * r * w[t * 2]);
    out[(size_t)row * HIDD + t * 2 + 1] = (__bf16)(v.y * r * w[t * 2 + 1]);
}

// ---------------- GEMM: C[M][N] = A[M][K] * Bt[N][K]^T ----------------
// BK template param; XOR source-swizzled LDS; XCD-aware block swizzle (T1).
template <int EPI, int TM, int TN, int BK>
__global__ __launch_bounds__(256) void gemm_bt(const __bf16* __restrict__ A,
                                               const __bf16* __restrict__ Bt,
                                               int M, int N, int K,
                                               __bf16* __restrict__ Cb,
                                               float* __restrict__ Cf,
                                               const float* __restrict__ resid,
                                               const float* __restrict__ scale,
                                               const float* __restrict__ cosv,
                                               const float* __restrict__ sinv) {
    __shared__ alignas(16) __bf16 As[TM][BK];
    __shared__ alignas(16) __bf16 Bs[TN][BK];
    constexpr int MI = TM / 32, NI = TN / 32;
    constexpr int CPB = BK / 8;
    int nwg = gridDim.x * gridDim.y;
    int bid = blockIdx.y * gridDim.x + blockIdx.x;
    int swz = (bid & 7) * (nwg >> 3) + (bid >> 3);
    int bx = swz % gridDim.x, by = swz / gridDim.x;
    int m0 = by * TM, n0 = bx * TN;
    int tid = threadIdx.x;
    int lane = tid & 63, w = tid >> 6;
    int wm = (w >> 1) * (TM / 2), wn = (w & 1) * (TN / 2);
    int lr = lane & 15, lkg = lane >> 4;
    f32x4 acc[MI][NI] = {};
    int nkt = K / BK;
    for (int kt = 0; kt < nkt; ++kt) {
        __syncthreads();
#pragma unroll
        for (int i = 0; i < (TM * BK) / 2048; ++i) {
            int c = i * 256 + tid;
            int row = c / CPB, ch = c % CPB;
            gload16(&A[(size_t)(m0 + row) * K + kt * BK + ((ch ^ (row & 7)) << 3)],
                    (__bf16*)As + c * 8);
        }
#pragma unroll
        for (int i = 0; i < (TN * BK) / 2048; ++i) {
            int c = i * 256 + tid;
            int row = c / CPB, ch = c % CPB;
            gload16(&Bt[(size_t)(n0 + row) * K + kt * BK + ((ch ^ (row & 7)) << 3)],
                    (__bf16*)Bs + c * 8);
        }
        __syncthreads();
#pragma unroll
        for (int kk = 0; kk < BK / 32; ++kk) {
            bf16x8 af[MI], bfv[NI];
#pragma unroll
            for (int mi = 0; mi < MI; ++mi) {
                int row = wm + mi * 16 + lr;
                af[mi] = *(const bf16x8*)&As[row][(((kk * 4 + lkg) ^ (row & 7)) << 3)];
            }
#pragma unroll
            for (int ni = 0; ni < NI; ++ni) {
                int row = wn + ni * 16 + lr;
                bfv[ni] = *(const bf16x8*)&Bs[row][(((kk * 4 + lkg) ^ (row & 7)) << 3)];
            }
#pragma unroll
            for (int mi = 0; mi < MI; ++mi)
#pragma unroll
                for (int ni = 0; ni < NI; ++ni)
                    acc[mi][ni] = __builtin_amdgcn_mfma_f32_16x16x32_bf16(
                        af[mi], bfv[ni], acc[mi][ni], 0, 0, 0);
        }
    }
    if (EPI == 1) {
        bool do_rope = (n0 + wn) < 2048;
        float qf = (n0 + wn) < 1024 ? QSCALE : 1.0f;
#pragma unroll
        for (int mi = 0; mi < MI; ++mi)
#pragma unroll
            for (int r = 0; r < 4; ++r) {
                int row = m0 + wm + mi * 16 + (lane >> 4) * 4 + r;
                int s = row & (SEQ - 1);
#pragma unroll
                for (int ni = 0; ni < 2; ++ni) {
                    float v1 = acc[mi][ni][r], v2 = acc[mi][ni + 2][r];
                    size_t i1 = (size_t)row * N + n0 + wn + ni * 16 + lr;
                    size_t i2 = i1 + 32;
                    if (do_rope) {
                        int d = ni * 16 + lr;
                        float c = cosv[s * 32 + d], sn = sinv[s * 32 + d];
                        Cb[i1] = (__bf16)((v1 * c - v2 * sn) * qf);
                        Cb[i2] = (__bf16)((v2 * c + v1 * sn) * qf);
                    } else {
                        Cb[i1] = (__bf16)v1;
                        Cb[i2] = (__bf16)v2;
                    }
                }
            }
    } else if (EPI == 3) {
#pragma unroll
        for (int mi = 0; mi < MI; ++mi)
#pragma unroll
            for (int r = 0; r < 4; ++r) {
                int row = m0 + wm + mi * 16 + (lane >> 4) * 4 + r;
#pragma unroll
                for (int ni = 0; ni < 4; ni += 2) {
                    float g = acc[mi][ni][r], u = acc[mi][ni + 1][r];
                    float mv = (g / (1.0f + __expf(-g))) * u;
                    int j = (((n0 + wn + ni * 16) >> 5) << 4) + lr;
                    Cb[(size_t)row * 1024 + j] = (__bf16)mv;
                }
            }
    } else {
#pragma unroll
        for (int mi = 0; mi < MI; ++mi)
#pragma unroll
            for (int ni = 0; ni < NI; ++ni)
#pragma unroll
                for (int r = 0; r < 4; ++r) {
                    int row = m0 + wm + mi * 16 + (lane >> 4) * 4 + r;
                    int col = n0 + wn + ni * 16 + lr;
                    size_t idx = (size_t)row * N + col;
                    float vv = acc[mi][ni][r];
                    if (EPI == 0) Cb[idx] = (__bf16)vv;
                    else          Cf[idx] = resid[idx] + vv * scale[col];
                }
    }
}

// ---------------- K/V repack: kill the 6KB-stride scatter in attn staging ----------------
// r15 diagnosis: attn iterations cost ~5800 cyc vs ~400 of issue; K/V staging
// at QKVN-stride = 64 cache lines per wave-instruction saturates the L1/TA
// line pipe. Repack ONCE: K -> kb[bh][s][64] (64-key tile = contiguous 8KB);
// V -> vtb[bh][dv][S] transposed AND pre-permuted with the exact inverse of
// the r15-verified vslot/vke map, so attn's PV fragment reads are unchanged.
__global__ __launch_bounds__(256) void kvprep_k(const __bf16* __restrict__ qkv,
                                                __bf16* __restrict__ kb,
                                                __bf16* __restrict__ vtb) {
    __shared__ __bf16 tr[64 * 132];
    int bh = blockIdx.x, st = blockIdx.y;
    int b = bh >> 4, h = bh & 15;
    size_t tok0 = (size_t)b * SEQ + st * 128;
    int tid = threadIdx.x;
    // K: strided-row copy (rope already applied by QKV epilogue)
#pragma unroll
    for (int i = 0; i < 4; ++i) {
        int c = i * 256 + tid;
        int kr = c >> 3, ch = c & 7;
        uint4 v = *(const uint4*)&qkv[(tok0 + kr) * QKVN + 1024 + h * 64 + ch * 8];
        *(uint4*)&kb[((size_t)bh * SEQ + st * 128 + kr) * 64 + ch * 8] = v;
    }
    // V: 128 tok x 64 dv -> LDS transposed
#pragma unroll
    for (int i = 0; i < 4; ++i) {
        int c = i * 256 + tid;
        int vr = c >> 3, ch = c & 7;
        uint4 v = *(const uint4*)&qkv[(tok0 + vr) * QKVN + 2048 + h * 64 + ch * 8];
        const __bf16* ve = (const __bf16*)&v;
#pragma unroll
        for (int j = 0; j < 8; ++j) tr[(ch * 8 + j) * 132 + vr] = ve[j];
    }
    __syncthreads();
    // write vtb rows with per-64-key-tile permutation:
    // chunk cc holds keys {K0..K0+3, K0+16..K0+19}, K0 = 32*(cc>>2)+4*(cc&3)
#pragma unroll
    for (int i = 0; i < 4; ++i) {
        int c = i * 256 + tid;
        int dv = c >> 4, rest = c & 15;
        int t64 = rest >> 3, cc = rest & 7;
        int K0 = t64 * 64 + 32 * (cc >> 2) + 4 * (cc & 3);
        __bf16 outv[8];
#pragma unroll
        for (int j = 0; j < 4; ++j) outv[j] = tr[dv * 132 + K0 + j];
#pragma unroll
        for (int j = 0; j < 4; ++j) outv[4 + j] = tr[dv * 132 + K0 + 16 + j];
        *(uint4*)&vtb[((size_t)bh * 64 + dv) * SEQ + st * 128 + t64 * 64 + cc * 8] =
            *(uint4*)outv;
    }
}

// ---------------- causal flash attention: dual wave-group, coalesced staging ----------------
// r15 structure (dual group, no spill) with K AND V staged via linear
// gload_lds from the compact kb/vtb buffers: wave staging loads now touch
// 8 x 128B lines instead of 64 -> ~8x less L1/TA line-processing per iter.
// V's reg-stage + 16 scalar ds_writes per thread deleted entirely.
__global__ __launch_bounds__(512, 4) void attn_k(const __bf16* __restrict__ qkv,
                                                 const __bf16* __restrict__ kb,
                                                 const __bf16* __restrict__ vtb,
                                                 __bf16* __restrict__ outp) {
    __shared__ alignas(16) __bf16 KS[2][2][4096];   // [grp][buf][64key x 64d]
    __shared__ alignas(16) __bf16 VS[2][2][4096];   // [grp][buf][64dv x 64key-perm]
    int bh = blockIdx.x;
    int b = bh >> 4, h = bh & 15;
    int y = blockIdx.y;                  // 0..15
    int qbA = y, qbB = 31 - y;
    int TA = y + 1;
    int tid = threadIdx.x;
    int grp = tid >> 8;
    int tg  = tid & 255;
    int lane = tid & 63, wg = tg >> 6;
    int lq = lane & 15, g = lane >> 4;
    size_t tokb = (size_t)b * SEQ;
    int qr0A = qbA * 64 + wg * 16, qr0B = qbB * 64 + wg * 16;

    bf16x8 ones8;
#pragma unroll
    for (int e = 0; e < 8; ++e) ones8[e] = (__bf16)1.0f;

    f32x4 oa[4] = {};
    f32x4 ol = {};

#define STAGE_K(kbn, kdst)                                                                         \
    {                                                                                              \
        _Pragma("unroll")                                                                          \
        for (int i = 0; i < 2; ++i) {                                                              \
            int c = i * 256 + tg;                                                                  \
            int kr = c >> 3, ch = c & 7;                                                           \
            gload16(&kb[((size_t)bh * SEQ + (kbn) * 64 + kr) * 64 + ((ch ^ (kr & 7)) << 3)],       \
                    (kdst) + c * 8);                                                               \
        }                                                                                          \
    }

#define STAGE_V(kbn, vdst)                                                                         \
    {                                                                                              \
        _Pragma("unroll")                                                                          \
        for (int i = 0; i < 2; ++i) {                                                              \
            int c = i * 256 + tg;                                                                  \
            int vr = c >> 3, ch = c & 7;                                                           \
            gload16(&vtb[((size_t)bh * 64 + vr) * SEQ + (kbn) * 64 + ((ch ^ (vr & 7)) << 3)],      \
                    (vdst) + c * 8);                                                               \
        }                                                                                          \
    }

#define QK_S(sc, aq, ksrc)                                                                         \
    {                                                                                              \
        __builtin_amdgcn_s_setprio(1);                                                             \
        _Pragma("unroll")                                                                          \
        for (int jt = 0; jt < 4; ++jt)                                                             \
            _Pragma("unroll")                                                                      \
            for (int ks = 0; ks < 2; ++ks) {                                                       \
                bf16x8 bk = *(const bf16x8*)&(ksrc)[(jt * 16 + lq) * 64 + (((ks * 4 + g) ^ (lq & 7)) << 3)]; \
                sc[jt] = __builtin_amdgcn_mfma_f32_16x16x32_bf16(bk, aq[ks], sc[jt], 0, 0, 0);     \
            }                                                                                      \
        __builtin_amdgcn_s_setprio(0);                                                             \
    }

#define MASK_S(sc, qr0_t, kb64)                                                                    \
    {                                                                                              \
        int qabs = (qr0_t) + lq;                                                                   \
        _Pragma("unroll")                                                                          \
        for (int jt = 0; jt < 4; ++jt)                                                             \
            _Pragma("unroll")                                                                      \
            for (int r = 0; r < 4; ++r) {                                                          \
                int key = (kb64) * 64 + jt * 16 + g * 4 + r;                                       \
                if (key > qabs) sc[jt][r] = -1e9f;                                                 \
            }                                                                                      \
    }

#define EXP_S(sc)                                                                                  \
    _Pragma("unroll")                                                                              \
    for (int jt = 0; jt < 4; ++jt)                                                                 \
        _Pragma("unroll")                                                                          \
        for (int r = 0; r < 4; ++r) sc[jt][r] = EXP2(sc[jt][r]);

#define PV_S(sc, vsrc)                                                                             \
    {                                                                                              \
        __builtin_amdgcn_s_setprio(1);                                                             \
        _Pragma("unroll")                                                                          \
        for (int ks2 = 0; ks2 < 2; ++ks2) {                                                        \
            bf16x8 pfv;                                                                            \
            _Pragma("unroll")                                                                      \
            for (int e = 0; e < 4; ++e) {                                                          \
                pfv[e]     = (__bf16)sc[2 * ks2][e];                                               \
                pfv[e + 4] = (__bf16)sc[2 * ks2 + 1][e];                                           \
            }                                                                                      \
            ol = __builtin_amdgcn_mfma_f32_16x16x32_bf16(ones8, pfv, ol, 0, 0, 0);                 \
            _Pragma("unroll")                                                                      \
            for (int dt = 0; dt < 4; ++dt) {                                                       \
                bf16x8 av = *(const bf16x8*)&(vsrc)[(dt * 16 + lq) * 64 + (((ks2 * 4 + g) ^ (lq & 7)) << 3)]; \
                oa[dt] = __builtin_amdgcn_mfma_f32_16x16x32_bf16(av, pfv, oa[dt], 0, 0, 0);        \
            }                                                                                      \
        }                                                                                          \
        __builtin_amdgcn_s_setprio(0);                                                             \
    }

    if (grp == 0) {
        // =================== group 0: tile B, kb 0..16 ===================
        bf16x8 aqB[2];
#pragma unroll
        for (int ks = 0; ks < 2; ++ks)
            aqB[ks] = *(const bf16x8*)&qkv[(tokb + qr0B + lq) * QKVN + h * 64 + ks * 32 + g * 8];
        STAGE_K(0, KS[0][0]);
        STAGE_V(0, VS[0][0]);
        __syncthreads();                               // barrier 0
        for (int it = 0; it < 17; ++it) {              // barriers 1..17
            int buf = it & 1;
            bool pf = it < 16;
            if (pf) {
                STAGE_K(it + 1, KS[0][buf ^ 1]);
                STAGE_V(it + 1, VS[0][buf ^ 1]);
            }
            f32x4 sc[4] = {};
            QK_S(sc, aqB, KS[0][buf]);
            if (it == qbB) MASK_S(sc, qr0B, it);
            EXP_S(sc);
            PV_S(sc, VS[0][buf]);
            __syncthreads();
        }
    } else {
        // =================== group 1: tile A (shared stream), then B-tail ===================
        {
            bf16x8 aqA[2];
#pragma unroll
            for (int ks = 0; ks < 2; ++ks)
                aqA[ks] = *(const bf16x8*)&qkv[(tokb + qr0A + lq) * QKVN + h * 64 + ks * 32 + g * 8];
            __syncthreads();                           // barrier 0
            for (int it = 0; it < TA; ++it) {          // barriers 1..TA
                int buf = it & 1;
                if (it == TA - 1) {                    // prepare B-tail stream
                    STAGE_K(17, KS[1][0]);
                    STAGE_V(17, VS[1][0]);
                }
                f32x4 sc[4] = {};
                QK_S(sc, aqA, KS[0][buf]);
                if (it == qbA) MASK_S(sc, qr0A, it);
                EXP_S(sc);
                PV_S(sc, VS[0][buf]);
                __syncthreads();
            }
        }
        // tile A epilogue (out of loop)
        {
            float inv = 1.0f / ol[0];
#pragma unroll
            for (int dt = 0; dt < 4; ++dt) {
                bf16x4 ov;
#pragma unroll
                for (int r = 0; r < 4; ++r) ov[r] = (__bf16)(oa[dt][r] * inv);
                *(bf16x4*)&outp[(tokb + qr0A + lq) * 1024 + h * 64 + dt * 16 + g * 4] = ov;
                oa[dt] = (f32x4){0.f, 0.f, 0.f, 0.f};
            }
            ol = (f32x4){0.f, 0.f, 0.f, 0.f};
        }
        // B-tail: kb 17..qbB, count = 16 - TA
        {
            bf16x8 aqB[2];
#pragma unroll
            for (int ks = 0; ks < 2; ++ks)
                aqB[ks] = *(const bf16x8*)&qkv[(tokb + qr0B + lq) * QKVN + h * 64 + ks * 32 + g * 8];
            int cnt = 16 - TA;
            for (int j = 0; j < cnt; ++j) {            // barriers TA+1..16
                int buf = j & 1;
                if (j + 1 < cnt) {
                    STAGE_K(17 + j + 1, KS[1][buf ^ 1]);
                    STAGE_V(17 + j + 1, VS[1][buf ^ 1]);
                }
                f32x4 sc[4] = {};
                int kb64 = 17 + j;
                QK_S(sc, aqB, KS[1][buf]);
                if (kb64 == qbB) MASK_S(sc, qr0B, kb64);
                EXP_S(sc);
                PV_S(sc, VS[1][buf]);
                __syncthreads();
            }
        }
        __syncthreads();                               // barrier 17 (equalize)
    }

    // ---- merge tile B partials (linear: just add) ----
    float* mrg_oa = (float*)KS[1];
    float* mrg_ol = (float*)VS[1];
    if (grp == 1) {
#pragma unroll
        for (int dt = 0; dt < 4; ++dt)
#pragma unroll
            for (int r = 0; r < 4; ++r) mrg_oa[tg * 16 + dt * 4 + r] = oa[dt][r];
        mrg_ol[tg] = ol[0];
    }
    __syncthreads();                                   // barrier 18
    if (grp == 0) {
        float l = ol[0] + mrg_ol[tg];
        float inv = 1.0f / l;
#pragma unroll
        for (int dt = 0; dt < 4; ++dt) {
            bf16x4 ov;
#pragma unroll
            for (int r = 0; r < 4; ++r)
                ov[r] = (__bf16)((oa[dt][r] + mrg_oa[tg * 16 + dt * 4 + r]) * inv);
            *(bf16x4*)&outp[(tokb + qr0B + lq) * 1024 + h * 64 + dt * 16 + g * 4] = ov;
        }
    }
#undef STAGE_K
#undef STAGE_V
#undef QK_S
#undef MASK_S
#undef EXP_S
#undef PV_S
}

// ---------------- launch ----------------
extern "C" void kernel_launch(void* const* d_in, const int* in_sizes, int n_in,
                              void* d_out, int out_size, void* d_ws, size_t ws_size,
                              hipStream_t stream) {
    const float* x       = (const float*)d_in[0];
    const float* cosv    = (const float*)d_in[1];
    const float* sinv    = (const float*)d_in[2];
    const float* wq      = (const float*)d_in[4];
    const float* wk      = (const float*)d_in[5];
    const float* wv      = (const float*)d_in[6];
    const float* wo      = (const float*)d_in[7];
    const float* wgate   = (const float*)d_in[8];
    const float* wup     = (const float*)d_in[9];
    const float* wdown   = (const float*)d_in[10];
    const float* norm1   = (const float*)d_in[11];
    const float* norm2   = (const float*)d_in[12];
    const float* ls_attn = (const float*)d_in[13];
    const float* ls_mlp  = (const float*)d_in[14];

    char* ws = (char*)d_ws;
    __bf16* wqkvT = (__bf16*)(ws + OFF_WQKVT);
    __bf16* woT   = (__bf16*)(ws + OFF_WOT);
    __bf16* wguT  = (__bf16*)(ws + OFF_WGUT);
    __bf16* wdT   = (__bf16*)(ws + OFF_WDT);
    __bf16* hb    = (__bf16*)(ws + OFF_HB);
    __bf16* qkvb  = (__bf16*)(ws + OFF_QKV);
    __bf16* attnb = (__bf16*)(ws + OFF_ATTN);
    float*  h2    = (float*)(ws + OFF_H2);
    __bf16* kbuf  = (__bf16*)(ws + OFF_H2);     // kb during attn (dead before h2)
    __bf16* vtbuf = (__bf16*)(ws + OFF_M);      // vtb during attn (dead before mb)
    __bf16* gb    = (__bf16*)(ws + OFF_G);
    __bf16* mb    = (__bf16*)(ws + OFF_M);
    float*  outf  = (float*)d_out;

    prep_k<<<7680, 256, 0, stream>>>(
        wq, wk, wv, wo, wgate, wup, wdown, wqkvT, woT, wguT, wdT, x, norm1, hb);
    gemm_bt<1, 128, 128, 64><<<dim3(QKVN / 128, NTOK / 128), 256, 0, stream>>>(
        hb, wqkvT, NTOK, QKVN, 512, qkvb, nullptr, nullptr, nullptr, cosv, sinv);
    kvprep_k<<<dim3(NB * NHEAD, SEQ / 128), 256, 0, stream>>>(qkvb, kbuf, vtbuf);
    attn_k<<<dim3(NB * NHEAD, 16), 512, 0, stream>>>(qkvb, kbuf, vtbuf, attnb);
    gemm_bt<2, 64, 64, 128><<<dim3(HIDD / 64, NTOK / 64), 256, 0, stream>>>(
        attnb, woT, NTOK, HIDD, 1024, nullptr, h2, x, ls_attn, nullptr, nullptr);
    rmsnorm_k<<<NTOK, 256, 0, stream>>>(h2, norm2, gb);
    gemm_bt<3, 128, 128, 64><<<dim3(GUN / 128, NTOK / 128), 256, 0, stream>>>(
        gb, wguT, NTOK, GUN, 512, mb, nullptr, nullptr, nullptr, nullptr, nullptr);
    gemm_bt<2, 64, 64, 128><<<dim3(HIDD / 64, NTOK / 64), 256, 0, stream>>>(
        mb, wdT, NTOK, HIDD, 1024, nullptr, outf, h2, ls_mlp, nullptr, nullptr);
}

// Round 17
// 105.639 us; speedup vs baseline: 1.4805x; 1.0589x over previous
//
#include <hip/hip_runtime.h>
#include <hip/hip_bf16.h>

typedef __bf16 bf16x8 __attribute__((ext_vector_type(8)));
typedef __bf16 bf16x4 __attribute__((ext_vector_type(4)));
typedef float f32x4 __attribute__((ext_vector_type(4)));

#define SEQ   2048
#define NB    2
#define NTOK  4096
#define HIDD  512
#define NHEAD 16
#define DHEAD 64
#define QKVN  3072
#define GUN   2048

// workspace layout (bytes)
#define OFF_WQKVT  0u
#define OFF_WOT    3145728u
#define OFF_WGUT   4194304u
#define OFF_WDT    6291456u
#define OFF_HB     7340032u
#define OFF_QB     11534336u                  // qb [4096][1024] bf16, 8.4MB
#define OFF_KB     (OFF_QB + 8388608u)        // kb [32][2048][64] bf16, 8.4MB
#define OFF_VB     (OFF_QB + 16777216u)       // vb [32][2048][64] bf16 (dead after kvprep -> mb)
#define OFF_ATTN   36700160u                  // attnb [4096][1024] bf16
#define OFF_H2     45088768u                  // vtb [32][64][2048] during attn; h2b bf16 after
#define OFF_G      53477376u                  // gb
#define OFF_M      OFF_VB                     // mb reuses vb region

#define QSCALE 0.1803368801111731f            // 0.125 * log2(e): exp2-domain scores

#if __has_builtin(__builtin_amdgcn_exp2f)
#define EXP2(x) __builtin_amdgcn_exp2f(x)
#else
#define EXP2(x) exp2f(x)
#endif

typedef unsigned int __attribute__((address_space(1))) as1_uint;
typedef unsigned int __attribute__((address_space(3))) as3_uint;
__device__ __forceinline__ void gload16(const void* g, void* l) {
    __builtin_amdgcn_global_load_lds((const as1_uint*)g, (as3_uint*)l, 16, 0, 0);
}

// ---------------- fused prep: 7 weight transposes + rmsnorm1, one launch ----
__global__ __launch_bounds__(256) void prep_k(
    const float* __restrict__ wq, const float* __restrict__ wk,
    const float* __restrict__ wv, const float* __restrict__ wo,
    const float* __restrict__ wg, const float* __restrict__ wu,
    const float* __restrict__ wd,
    __bf16* __restrict__ qkvT, __bf16* __restrict__ woT,
    __bf16* __restrict__ wguT, __bf16* __restrict__ wdT,
    const float* __restrict__ x, const float* __restrict__ norm1,
    __bf16* __restrict__ hb) {
    __shared__ float t[32][33];
    int bid = blockIdx.x;
    if (bid < 3584) {
        int which = bid >> 9, bx = bid & 511;
        const float* in; __bf16* out; int K, N, mode = 0, phase = 0;
        switch (which) {
            case 0: in = wq; out = qkvT;              K = 512;  N = 1024; break;
            case 1: in = wk; out = qkvT + 1024 * 512; K = 512;  N = 1024; break;
            case 2: in = wv; out = qkvT + 2048 * 512; K = 512;  N = 1024; break;
            case 3: in = wo; out = woT;               K = 1024; N = 512;  break;
            case 4: in = wg; out = wguT;              K = 512;  N = 1024; mode = 1; phase = 0; break;
            case 5: in = wu; out = wguT;              K = 512;  N = 1024; mode = 1; phase = 1; break;
            default: in = wd; out = wdT;              K = 1024; N = 512;  break;
        }
        int ntn = N >> 5;
        int n0 = (bx & (ntn - 1)) * 32;
        int k0 = (bx / ntn) * 32;
        int tx = threadIdx.x & 31, ty = threadIdx.x >> 5;
#pragma unroll
        for (int j = 0; j < 4; ++j)
            t[ty * 4 + j][tx] = in[(size_t)(k0 + ty * 4 + j) * N + n0 + tx];
        __syncthreads();
#pragma unroll
        for (int j = 0; j < 4; ++j) {
            int n = n0 + ty * 4 + j;
            int row = mode ? (((n >> 4) << 5) + phase * 16 + (n & 15)) : n;
            out[(size_t)row * K + k0 + tx] = (__bf16)t[tx][ty * 4 + j];
        }
    } else {
        int row = bid - 3584;
        int tt = threadIdx.x;
        const float* xr = x + (size_t)row * HIDD;
        float2 v = *(const float2*)&xr[tt * 2];
        float ss = v.x * v.x + v.y * v.y;
#pragma unroll
        for (int off = 32; off >= 1; off >>= 1) ss += __shfl_xor(ss, off);
        if ((tt & 63) == 0) t[0][tt >> 6] = ss;
        __syncthreads();
        float tot = t[0][0] + t[0][1] + t[0][2] + t[0][3];
        float r = rsqrtf(tot * (1.0f / HIDD) + 1e-8f);
        hb[(size_t)row * HIDD + tt * 2]     = (__bf16)(v.x * r * norm1[tt * 2]);
        hb[(size_t)row * HIDD + tt * 2 + 1] = (__bf16)(v.y * r * norm1[tt * 2 + 1]);
    }
}

// ---------------- RMSNorm over bf16 input (norm2) ----------------
__global__ __launch_bounds__(256) void rmsnorm_bk(const __bf16* __restrict__ x,
                                                  const float* __restrict__ w,
                                                  __bf16* __restrict__ out) {
    int row = blockIdx.x;
    int t = threadIdx.x;
    const __bf16* xr = x + (size_t)row * HIDD;
    float v0 = (float)xr[t * 2], v1 = (float)xr[t * 2 + 1];
    float ss = v0 * v0 + v1 * v1;
#pragma unroll
    for (int off = 32; off >= 1; off >>= 1) ss += __shfl_xor(ss, off);
    __shared__ float red[4];
    if ((t & 63) == 0) red[t >> 6] = ss;
    __syncthreads();
    float tot = red[0] + red[1] + red[2] + red[3];
    float r = rsqrtf(tot * (1.0f / HIDD) + 1e-8f);
    out[(size_t)row * HIDD + t * 2]     = (__bf16)(v0 * r * w[t * 2]);
    out[(size_t)row * HIDD + t * 2 + 1] = (__bf16)(v1 * r * w[t * 2 + 1]);
}

// ---------------- GEMM: C[M][N] = A[M][K] * Bt[N][K]^T ----------------
// EPI 1: QKV -> compact qb/kb/vb with rope (kvprep K-copy deleted).
// EPI 3: silu(gate)*up. EPI 4: bf16 out = f32 resid + acc*scale.
// EPI 5: f32 out = bf16 resid (in Cb) + acc*scale.
template <int EPI, int TM, int TN, int BK>
__global__ __launch_bounds__(256) void gemm_bt(const __bf16* __restrict__ A,
                                               const __bf16* __restrict__ Bt,
                                               int M, int N, int K,
                                               __bf16* __restrict__ Cb,
                                               float* __restrict__ Cf,
                                               const float* __restrict__ resid,
                                               const float* __restrict__ scale,
                                               const float* __restrict__ cosv,
                                               const float* __restrict__ sinv,
                                               __bf16* __restrict__ kbp,
                                               __bf16* __restrict__ vbp) {
    __shared__ alignas(16) __bf16 As[TM][BK];
    __shared__ alignas(16) __bf16 Bs[TN][BK];
    constexpr int MI = TM / 32, NI = TN / 32;
    constexpr int CPB = BK / 8;
    int nwg = gridDim.x * gridDim.y;
    int bid = blockIdx.y * gridDim.x + blockIdx.x;
    int swz = (bid & 7) * (nwg >> 3) + (bid >> 3);
    int bx = swz % gridDim.x, by = swz / gridDim.x;
    int m0 = by * TM, n0 = bx * TN;
    int tid = threadIdx.x;
    int lane = tid & 63, w = tid >> 6;
    int wm = (w >> 1) * (TM / 2), wn = (w & 1) * (TN / 2);
    int lr = lane & 15, lkg = lane >> 4;
    f32x4 acc[MI][NI] = {};
    int nkt = K / BK;
    for (int kt = 0; kt < nkt; ++kt) {
        __syncthreads();
#pragma unroll
        for (int i = 0; i < (TM * BK) / 2048; ++i) {
            int c = i * 256 + tid;
            int row = c / CPB, ch = c % CPB;
            gload16(&A[(size_t)(m0 + row) * K + kt * BK + ((ch ^ (row & 7)) << 3)],
                    (__bf16*)As + c * 8);
        }
#pragma unroll
        for (int i = 0; i < (TN * BK) / 2048; ++i) {
            int c = i * 256 + tid;
            int row = c / CPB, ch = c % CPB;
            gload16(&Bt[(size_t)(n0 + row) * K + kt * BK + ((ch ^ (row & 7)) << 3)],
                    (__bf16*)Bs + c * 8);
        }
        __syncthreads();
#pragma unroll
        for (int kk = 0; kk < BK / 32; ++kk) {
            bf16x8 af[MI], bfv[NI];
#pragma unroll
            for (int mi = 0; mi < MI; ++mi) {
                int row = wm + mi * 16 + lr;
                af[mi] = *(const bf16x8*)&As[row][(((kk * 4 + lkg) ^ (row & 7)) << 3)];
            }
#pragma unroll
            for (int ni = 0; ni < NI; ++ni) {
                int row = wn + ni * 16 + lr;
                bfv[ni] = *(const bf16x8*)&Bs[row][(((kk * 4 + lkg) ^ (row & 7)) << 3)];
            }
#pragma unroll
            for (int mi = 0; mi < MI; ++mi)
#pragma unroll
                for (int ni = 0; ni < NI; ++ni)
                    acc[mi][ni] = __builtin_amdgcn_mfma_f32_16x16x32_bf16(
                        af[mi], bfv[ni], acc[mi][ni], 0, 0, 0);
        }
    }
    if (EPI == 1) {
        int col0 = n0 + wn;                 // 64-aligned -> single head, single region
        int hh = (col0 >> 6) & 15;
#pragma unroll
        for (int mi = 0; mi < MI; ++mi)
#pragma unroll
            for (int r = 0; r < 4; ++r) {
                int row = m0 + wm + mi * 16 + lkg * 4 + r;
                int s = row & (SEQ - 1);
                size_t hdr = ((size_t)((row >> 11) * 16 + hh) * SEQ + s) * 64;
                if (col0 < 1024) {          // Q: rope * QSCALE -> qb
#pragma unroll
                    for (int ni = 0; ni < 2; ++ni) {
                        float v1 = acc[mi][ni][r], v2 = acc[mi][ni + 2][r];
                        int d = ni * 16 + lr;
                        float c = cosv[s * 32 + d], sn = sinv[s * 32 + d];
                        size_t i1 = (size_t)row * 1024 + col0 + d;
                        Cb[i1]      = (__bf16)((v1 * c - v2 * sn) * QSCALE);
                        Cb[i1 + 32] = (__bf16)((v2 * c + v1 * sn) * QSCALE);
                    }
                } else if (col0 < 2048) {   // K: rope -> kb compact
#pragma unroll
                    for (int ni = 0; ni < 2; ++ni) {
                        float v1 = acc[mi][ni][r], v2 = acc[mi][ni + 2][r];
                        int d = ni * 16 + lr;
                        float c = cosv[s * 32 + d], sn = sinv[s * 32 + d];
                        kbp[hdr + d]      = (__bf16)(v1 * c - v2 * sn);
                        kbp[hdr + d + 32] = (__bf16)(v2 * c + v1 * sn);
                    }
                } else {                    // V: plain -> vb compact
#pragma unroll
                    for (int ni = 0; ni < 4; ++ni)
                        vbp[hdr + ni * 16 + lr] = (__bf16)acc[mi][ni][r];
                }
            }
    } else if (EPI == 3) {
#pragma unroll
        for (int mi = 0; mi < MI; ++mi)
#pragma unroll
            for (int r = 0; r < 4; ++r) {
                int row = m0 + wm + mi * 16 + lkg * 4 + r;
#pragma unroll
                for (int ni = 0; ni < 4; ni += 2) {
                    float g = acc[mi][ni][r], u = acc[mi][ni + 1][r];
                    float mv = (g / (1.0f + __expf(-g))) * u;
                    int j = (((n0 + wn + ni * 16) >> 5) << 4) + lr;
                    Cb[(size_t)row * 1024 + j] = (__bf16)mv;
                }
            }
    } else if (EPI == 4) {                  // bf16 out = f32 resid + acc*scale
#pragma unroll
        for (int mi = 0; mi < MI; ++mi)
#pragma unroll
            for (int ni = 0; ni < NI; ++ni)
#pragma unroll
                for (int r = 0; r < 4; ++r) {
                    int row = m0 + wm + mi * 16 + lkg * 4 + r;
                    int col = n0 + wn + ni * 16 + lr;
                    size_t idx = (size_t)row * N + col;
                    Cb[idx] = (__bf16)(resid[idx] + acc[mi][ni][r] * scale[col]);
                }
    } else if (EPI == 5) {                  // f32 out = bf16 resid(Cb) + acc*scale
        const __bf16* rb = (const __bf16*)Cb;
#pragma unroll
        for (int mi = 0; mi < MI; ++mi)
#pragma unroll
            for (int ni = 0; ni < NI; ++ni)
#pragma unroll
                for (int r = 0; r < 4; ++r) {
                    int row = m0 + wm + mi * 16 + lkg * 4 + r;
                    int col = n0 + wn + ni * 16 + lr;
                    size_t idx = (size_t)row * N + col;
                    Cf[idx] = (float)rb[idx] + acc[mi][ni][r] * scale[col];
                }
    }
}

// ---------------- V transpose+permute (K copy deleted; QKV writes kb direct) ----
__global__ __launch_bounds__(256) void kvprep_k(const __bf16* __restrict__ vb,
                                                __bf16* __restrict__ vtb) {
    __shared__ __bf16 tr[64 * 132];
    int bh = blockIdx.x, st = blockIdx.y;
    int tid = threadIdx.x;
    size_t base = ((size_t)bh * SEQ + st * 128) * 64;
#pragma unroll
    for (int i = 0; i < 4; ++i) {
        int c = i * 256 + tid;
        int vr = c >> 3, ch = c & 7;
        uint4 v = *(const uint4*)&vb[base + (size_t)vr * 64 + ch * 8];
        const __bf16* ve = (const __bf16*)&v;
#pragma unroll
        for (int j = 0; j < 8; ++j) tr[(ch * 8 + j) * 132 + vr] = ve[j];
    }
    __syncthreads();
    // per-64-key-tile permutation: chunk cc holds keys {K0..K0+3, K0+16..K0+19}
#pragma unroll
    for (int i = 0; i < 4; ++i) {
        int c = i * 256 + tid;
        int dv = c >> 4, rest = c & 15;
        int t64 = rest >> 3, cc = rest & 7;
        int K0 = t64 * 64 + 32 * (cc >> 2) + 4 * (cc & 3);
        __bf16 outv[8];
#pragma unroll
        for (int j = 0; j < 4; ++j) outv[j] = tr[dv * 132 + K0 + j];
#pragma unroll
        for (int j = 0; j < 4; ++j) outv[4 + j] = tr[dv * 132 + K0 + 16 + j];
        *(uint4*)&vtb[((size_t)bh * 64 + dv) * SEQ + st * 128 + t64 * 64 + cc * 8] =
            *(uint4*)outv;
    }
}

// ---------------- causal flash attention: dual wave-group, coalesced staging ----------------
__global__ __launch_bounds__(512, 4) void attn_k(const __bf16* __restrict__ qb,
                                                 const __bf16* __restrict__ kb,
                                                 const __bf16* __restrict__ vtb,
                                                 __bf16* __restrict__ outp) {
    __shared__ alignas(16) __bf16 KS[2][2][4096];
    __shared__ alignas(16) __bf16 VS[2][2][4096];
    int bh = blockIdx.x;
    int b = bh >> 4, h = bh & 15;
    int y = blockIdx.y;
    int qbA = y, qbB = 31 - y;
    int TA = y + 1;
    int tid = threadIdx.x;
    int grp = tid >> 8;
    int tg  = tid & 255;
    int lane = tid & 63, wg = tg >> 6;
    int lq = lane & 15, g = lane >> 4;
    size_t tokb = (size_t)b * SEQ;
    int qr0A = qbA * 64 + wg * 16, qr0B = qbB * 64 + wg * 16;

    bf16x8 ones8;
#pragma unroll
    for (int e = 0; e < 8; ++e) ones8[e] = (__bf16)1.0f;

    f32x4 oa[4] = {};
    f32x4 ol = {};

#define STAGE_K(kbn, kdst)                                                                         \
    {                                                                                              \
        _Pragma("unroll")                                                                          \
        for (int i = 0; i < 2; ++i) {                                                              \
            int c = i * 256 + tg;                                                                  \
            int kr = c >> 3, ch = c & 7;                                                           \
            gload16(&kb[((size_t)bh * SEQ + (kbn) * 64 + kr) * 64 + ((ch ^ (kr & 7)) << 3)],       \
                    (kdst) + c * 8);                                                               \
        }                                                                                          \
    }

#define STAGE_V(kbn, vdst)                                                                         \
    {                                                                                              \
        _Pragma("unroll")                                                                          \
        for (int i = 0; i < 2; ++i) {                                                              \
            int c = i * 256 + tg;                                                                  \
            int vr = c >> 3, ch = c & 7;                                                           \
            gload16(&vtb[((size_t)bh * 64 + vr) * SEQ + (kbn) * 64 + ((ch ^ (vr & 7)) << 3)],      \
                    (vdst) + c * 8);                                                               \
        }                                                                                          \
    }

#define QK_S(sc, aq, ksrc)                                                                         \
    {                                                                                              \
        __builtin_amdgcn_s_setprio(1);                                                             \
        _Pragma("unroll")                                                                          \
        for (int jt = 0; jt < 4; ++jt)                                                             \
            _Pragma("unroll")                                                                      \
            for (int ks = 0; ks < 2; ++ks) {                                                       \
                bf16x8 bk = *(const bf16x8*)&(ksrc)[(jt * 16 + lq) * 64 + (((ks * 4 + g) ^ (lq & 7)) << 3)]; \
                sc[jt] = __builtin_amdgcn_mfma_f32_16x16x32_bf16(bk, aq[ks], sc[jt], 0, 0, 0);     \
            }                                                                                      \
        __builtin_amdgcn_s_setprio(0);                                                             \
    }

#define MASK_S(sc, qr0_t, kb64)                                                                    \
    {                                                                                              \
        int qabs = (qr0_t) + lq;                                                                   \
        _Pragma("unroll")                                                                          \
        for (int jt = 0; jt < 4; ++jt)                                                             \
            _Pragma("unroll")                                                                      \
            for (int r = 0; r < 4; ++r) {                                                          \
                int key = (kb64) * 64 + jt * 16 + g * 4 + r;                                       \
                if (key > qabs) sc[jt][r] = -1e9f;                                                 \
            }                                                                                      \
    }

#define EXP_S(sc)                                                                                  \
    _Pragma("unroll")                                                                              \
    for (int jt = 0; jt < 4; ++jt)                                                                 \
        _Pragma("unroll")                                                                          \
        for (int r = 0; r < 4; ++r) sc[jt][r] = EXP2(sc[jt][r]);

#define PV_S(sc, vsrc)                                                                             \
    {                                                                                              \
        __builtin_amdgcn_s_setprio(1);                                                             \
        _Pragma("unroll")                                                                          \
        for (int ks2 = 0; ks2 < 2; ++ks2) {                                                        \
            bf16x8 pfv;                                                                            \
            _Pragma("unroll")                                                                      \
            for (int e = 0; e < 4; ++e) {                                                          \
                pfv[e]     = (__bf16)sc[2 * ks2][e];                                               \
                pfv[e + 4] = (__bf16)sc[2 * ks2 + 1][e];                                           \
            }                                                                                      \
            ol = __builtin_amdgcn_mfma_f32_16x16x32_bf16(ones8, pfv, ol, 0, 0, 0);                 \
            _Pragma("unroll")                                                                      \
            for (int dt = 0; dt < 4; ++dt) {                                                       \
                bf16x8 av = *(const bf16x8*)&(vsrc)[(dt * 16 + lq) * 64 + (((ks2 * 4 + g) ^ (lq & 7)) << 3)]; \
                oa[dt] = __builtin_amdgcn_mfma_f32_16x16x32_bf16(av, pfv, oa[dt], 0, 0, 0);        \
            }                                                                                      \
        }                                                                                          \
        __builtin_amdgcn_s_setprio(0);                                                             \
    }

    if (grp == 0) {
        // =================== group 0: tile B, kb 0..16 ===================
        bf16x8 aqB[2];
#pragma unroll
        for (int ks = 0; ks < 2; ++ks)
            aqB[ks] = *(const bf16x8*)&qb[(tokb + qr0B + lq) * 1024 + h * 64 + ks * 32 + g * 8];
        STAGE_K(0, KS[0][0]);
        STAGE_V(0, VS[0][0]);
        __syncthreads();                               // barrier 0
        for (int it = 0; it < 17; ++it) {              // barriers 1..17
            int buf = it & 1;
            bool pf = it < 16;
            if (pf) {
                STAGE_K(it + 1, KS[0][buf ^ 1]);
                STAGE_V(it + 1, VS[0][buf ^ 1]);
            }
            f32x4 sc[4] = {};
            QK_S(sc, aqB, KS[0][buf]);
            if (it == qbB) MASK_S(sc, qr0B, it);
            EXP_S(sc);
            PV_S(sc, VS[0][buf]);
            __syncthreads();
        }
    } else {
        // =================== group 1: tile A (shared stream), then B-tail ===================
        {
            bf16x8 aqA[2];
#pragma unroll
            for (int ks = 0; ks < 2; ++ks)
                aqA[ks] = *(const bf16x8*)&qb[(tokb + qr0A + lq) * 1024 + h * 64 + ks * 32 + g * 8];
            __syncthreads();                           // barrier 0
            for (int it = 0; it < TA; ++it) {          // barriers 1..TA
                int buf = it & 1;
                if (it == TA - 1) {                    // prepare B-tail stream
                    STAGE_K(17, KS[1][0]);
                    STAGE_V(17, VS[1][0]);
                }
                f32x4 sc[4] = {};
                QK_S(sc, aqA, KS[0][buf]);
                if (it == qbA) MASK_S(sc, qr0A, it);
                EXP_S(sc);
                PV_S(sc, VS[0][buf]);
                __syncthreads();
            }
        }
        // tile A epilogue
        {
            float inv = 1.0f / ol[0];
#pragma unroll
            for (int dt = 0; dt < 4; ++dt) {
                bf16x4 ov;
#pragma unroll
                for (int r = 0; r < 4; ++r) ov[r] = (__bf16)(oa[dt][r] * inv);
                *(bf16x4*)&outp[(tokb + qr0A + lq) * 1024 + h * 64 + dt * 16 + g * 4] = ov;
                oa[dt] = (f32x4){0.f, 0.f, 0.f, 0.f};
            }
            ol = (f32x4){0.f, 0.f, 0.f, 0.f};
        }
        // B-tail: kb 17..qbB
        {
            bf16x8 aqB[2];
#pragma unroll
            for (int ks = 0; ks < 2; ++ks)
                aqB[ks] = *(const bf16x8*)&qb[(tokb + qr0B + lq) * 1024 + h * 64 + ks * 32 + g * 8];
            int cnt = 16 - TA;
            for (int j = 0; j < cnt; ++j) {            // barriers TA+1..16
                int buf = j & 1;
                if (j + 1 < cnt) {
                    STAGE_K(17 + j + 1, KS[1][buf ^ 1]);
                    STAGE_V(17 + j + 1, VS[1][buf ^ 1]);
                }
                f32x4 sc[4] = {};
                int kb64 = 17 + j;
                QK_S(sc, aqB, KS[1][buf]);
                if (kb64 == qbB) MASK_S(sc, qr0B, kb64);
                EXP_S(sc);
                PV_S(sc, VS[1][buf]);
                __syncthreads();
            }
        }
        __syncthreads();                               // barrier 17 (equalize)
    }

    // ---- merge tile B partials (linear: just add) ----
    float* mrg_oa = (float*)KS[1];
    float* mrg_ol = (float*)VS[1];
    if (grp == 1) {
#pragma unroll
        for (int dt = 0; dt < 4; ++dt)
#pragma unroll
            for (int r = 0; r < 4; ++r) mrg_oa[tg * 16 + dt * 4 + r] = oa[dt][r];
        mrg_ol[tg] = ol[0];
    }
    __syncthreads();                                   // barrier 18
    if (grp == 0) {
        float l = ol[0] + mrg_ol[tg];
        float inv = 1.0f / l;
#pragma unroll
        for (int dt = 0; dt < 4; ++dt) {
            bf16x4 ov;
#pragma unroll
            for (int r = 0; r < 4; ++r)
                ov[r] = (__bf16)((oa[dt][r] + mrg_oa[tg * 16 + dt * 4 + r]) * inv);
            *(bf16x4*)&outp[(tokb + qr0B + lq) * 1024 + h * 64 + dt * 16 + g * 4] = ov;
        }
    }
#undef STAGE_K
#undef STAGE_V
#undef QK_S
#undef MASK_S
#undef EXP_S
#undef PV_S
}

// ---------------- launch ----------------
extern "C" void kernel_launch(void* const* d_in, const int* in_sizes, int n_in,
                              void* d_out, int out_size, void* d_ws, size_t ws_size,
                              hipStream_t stream) {
    const float* x       = (const float*)d_in[0];
    const float* cosv    = (const float*)d_in[1];
    const float* sinv    = (const float*)d_in[2];
    const float* wq      = (const float*)d_in[4];
    const float* wk      = (const float*)d_in[5];
    const float* wv      = (const float*)d_in[6];
    const float* wo      = (const float*)d_in[7];
    const float* wgate   = (const float*)d_in[8];
    const float* wup     = (const float*)d_in[9];
    const float* wdown   = (const float*)d_in[10];
    const float* norm1   = (const float*)d_in[11];
    const float* norm2   = (const float*)d_in[12];
    const float* ls_attn = (const float*)d_in[13];
    const float* ls_mlp  = (const float*)d_in[14];

    char* ws = (char*)d_ws;
    __bf16* wqkvT = (__bf16*)(ws + OFF_WQKVT);
    __bf16* woT   = (__bf16*)(ws + OFF_WOT);
    __bf16* wguT  = (__bf16*)(ws + OFF_WGUT);
    __bf16* wdT   = (__bf16*)(ws + OFF_WDT);
    __bf16* hb    = (__bf16*)(ws + OFF_HB);
    __bf16* qbuf  = (__bf16*)(ws + OFF_QB);
    __bf16* kbuf  = (__bf16*)(ws + OFF_KB);
    __bf16* vbuf  = (__bf16*)(ws + OFF_VB);
    __bf16* vtbuf = (__bf16*)(ws + OFF_H2);     // vtb during attn
    __bf16* attnb = (__bf16*)(ws + OFF_ATTN);
    __bf16* h2b   = (__bf16*)(ws + OFF_H2);     // bf16 h2 after attn (vtb dead)
    __bf16* gb    = (__bf16*)(ws + OFF_G);
    __bf16* mb    = (__bf16*)(ws + OFF_M);      // reuses vb region
    float*  outf  = (float*)d_out;

    prep_k<<<7680, 256, 0, stream>>>(
        wq, wk, wv, wo, wgate, wup, wdown, wqkvT, woT, wguT, wdT, x, norm1, hb);
    gemm_bt<1, 128, 128, 64><<<dim3(QKVN / 128, NTOK / 128), 256, 0, stream>>>(
        hb, wqkvT, NTOK, QKVN, 512, qbuf, nullptr, nullptr, nullptr, cosv, sinv, kbuf, vbuf);
    kvprep_k<<<dim3(NB * NHEAD, SEQ / 128), 256, 0, stream>>>(vbuf, vtbuf);
    attn_k<<<dim3(NB * NHEAD, 16), 512, 0, stream>>>(qbuf, kbuf, vtbuf, attnb);
    gemm_bt<4, 64, 64, 128><<<dim3(HIDD / 64, NTOK / 64), 256, 0, stream>>>(
        attnb, woT, NTOK, HIDD, 1024, h2b, nullptr, x, ls_attn, nullptr, nullptr, nullptr, nullptr);
    rmsnorm_bk<<<NTOK, 256, 0, stream>>>(h2b, norm2, gb);
    gemm_bt<3, 128, 128, 64><<<dim3(GUN / 128, NTOK / 128), 256, 0, stream>>>(
        gb, wguT, NTOK, GUN, 512, mb, nullptr, nullptr, nullptr, nullptr, nullptr, nullptr, nullptr);
    gemm_bt<5, 64, 64, 128><<<dim3(HIDD / 64, NTOK / 64), 256, 0, stream>>>(
        mb, wdT, NTOK, HIDD, 1024, h2b, outf, nullptr, ls_mlp, nullptr, nullptr, nullptr, nullptr);
}